// Round 19
// baseline (809.734 us; speedup 1.0000x reference)
//
#include <hip/hip_runtime.h>
#include <hip/hip_cooperative_groups.h>
namespace cg = cooperative_groups;

#define NLK 65536
#define NN (NLK * 4)        // 262144 nodes
#define DYNF 32
#define STATF 8
#define GG 64
#define EUP 4194304
#define EIN 1048576
#define EFB 1048576

// unified row space: [up: NN][inner: 4*NLK][fwd: 3*2NLK][bwd: 3*2NLK]
#define NS_UP    0
#define NS_IN(l) (NN + (l) * NLK)
#define NS_F(l)  (NN + 4 * NLK + (l) * 2 * NLK)
#define NS_B(l)  (NN + 10 * NLK + (l) * 2 * NLK)
#define NS_TOT   (NN + 16 * NLK)                    // 1,310,720
#define CO_TOT   (EUP + 4 * EIN + 6 * EFB)          // 14,680,064

#define CHUNK 32768                                 // edges per partition block
#define NB    (CO_TOT / CHUNK)                      // 448 partition blocks
#define BROWS 1024                                  // rows per bucket
#define NBUCK (NS_TOT / BROWS)                      // 1280 buckets
#define HM    (NBUCK * NB)                          // 573,440
#define SCAP  20480                                 // group LDS sort capacity

// pack-pool slot offsets (u32 units)
#define SLOT_U (NLK * 16)
#define SA_O 0
#define SB_O (1 * SLOT_U)
#define SC_O (2 * SLOT_U)
#define SD_O (3 * SLOT_U)
#define F0_O (4 * SLOT_U)
#define F1_O (6 * SLOT_U)
#define F2_O (8 * SLOT_U)
#define B0_O (10 * SLOT_U)
#define B1_O (12 * SLOT_U)
#define B2_O (14 * SLOT_U)

#define MBLK 256                                    // mega grid: 1 block/CU guaranteed
#define MTHR 1024

static inline int cdiv(long a, int b) { return (int)((a + b - 1) / b); }

// ---- which list does partition block b cover? --------------------------
__device__ inline void cdecode(int b, const int* e_up, const int* e_in,
                               const int* e_f, const int* e_b,
                               const int*& srcp, const int*& dstp, int& ns, int& e0) {
    if (b < EUP / CHUNK) { srcp = e_up; dstp = e_up + EUP; ns = NS_UP; e0 = b * CHUNK; return; }
    int t = b - EUP / CHUNK;
    int list = t >> 5;                               // 32 blocks per small list
    e0 = (t & 31) * CHUNK;
    if (list < 4) {
        srcp = e_in + (size_t)(2 * list) * EIN; dstp = srcp + EIN; ns = NS_IN(list);
    } else if (list < 7) {
        int l = list - 4;
        srcp = e_f + (size_t)(2 * l) * EFB; dstp = srcp + EFB; ns = NS_F(l);
    } else {
        int l = list - 7;
        srcp = e_b + (size_t)(2 * l) * EFB; dstp = srcp + EFB; ns = NS_B(l);
    }
}

// ---- pass 1: per-block LDS bucket histogram (1024 threads) -------------
__global__ void hist_part_kernel(const int* __restrict__ e_up, const int* __restrict__ e_in,
                                 const int* __restrict__ e_f, const int* __restrict__ e_b,
                                 int* __restrict__ hmat) {
    __shared__ int lh[NBUCK];
    for (int k = threadIdx.x; k < NBUCK; k += 1024) lh[k] = 0;
    __syncthreads();
    const int *srcp, *dstp; int ns, e0;
    cdecode(blockIdx.x, e_up, e_in, e_f, e_b, srcp, dstp, ns, e0);
    for (int j = 0; j < CHUNK / 1024; j++) {
        int g = ns + dstp[e0 + j * 1024 + threadIdx.x];
        atomicAdd(&lh[g >> 10], 1);
    }
    __syncthreads();
    for (int k = threadIdx.x; k < NBUCK; k += 1024)
        hmat[(size_t)k * NB + blockIdx.x] = lh[k];
}

// ---- pass 2: LDS-staged bucket sort -> coalesced slice flush -----------
__global__ void scatter_part_kernel(const int* __restrict__ e_up, const int* __restrict__ e_in,
                                    const int* __restrict__ e_f, const int* __restrict__ e_b,
                                    const int* __restrict__ hmat, const int* __restrict__ smat,
                                    unsigned* __restrict__ pairs) {
    __shared__ unsigned srt[CHUNK];                 // 128 KB
    __shared__ int ls[NBUCK + 1];
    __shared__ int gbase[NBUCK];
    __shared__ int lcur[NBUCK];
    __shared__ int ssum[1024];
    int t = threadIdx.x;
    int b = blockIdx.x;
    const int *srcp, *dstp; int ns, e0;
    cdecode(b, e_up, e_in, e_f, e_b, srcp, dstp, ns, e0);
    int a0 = (2 * t < NBUCK) ? hmat[(size_t)(2 * t) * NB + b] : 0;
    int a1 = (2 * t + 1 < NBUCK) ? hmat[(size_t)(2 * t + 1) * NB + b] : 0;
    if (2 * t < NBUCK) gbase[2 * t] = smat[(size_t)(2 * t) * NB + b];
    if (2 * t + 1 < NBUCK) gbase[2 * t + 1] = smat[(size_t)(2 * t + 1) * NB + b];
    if (2 * t < NBUCK) lcur[2 * t] = 0;
    if (2 * t + 1 < NBUCK) lcur[2 * t + 1] = 0;
    int gsum = a0 + a1;
    ssum[t] = gsum;
    __syncthreads();
    for (int off = 1; off < 1024; off <<= 1) {
        int u = (t >= off) ? ssum[t - off] : 0;
        __syncthreads();
        ssum[t] += u;
        __syncthreads();
    }
    int run = ssum[t] - gsum;
    if (2 * t < NBUCK) ls[2 * t] = run;
    if (2 * t + 1 < NBUCK) ls[2 * t + 1] = run + a0;
    if (t == 0) ls[NBUCK] = CHUNK;                  // sentinel
    __syncthreads();
    for (int j = 0; j < CHUNK / 1024; j++) {
        int el = e0 + j * 1024 + t;
        int g = ns + dstp[el];
        int s = srcp[el];
        int k = g >> 10;
        int pos = ls[k] + atomicAdd(&lcur[k], 1);
        srt[pos] = ((unsigned)s << 10) | (unsigned)(g & (BROWS - 1));
    }
    __syncthreads();
    int wave = t >> 6;
    int lane = t & 63;
    for (int k = wave; k < NBUCK; k += 16) {
        int lo = ls[k];
        int n = ls[k + 1] - lo;
        int dst = gbase[k];
        for (int i = lane; i < n; i += 64)
            pairs[dst + i] = srt[lo + i];
    }
}

// ---- pass 3: per-bucket group; LDS-staged sort -> sequential col (1024 thr)
__global__ void group_kernel(const unsigned* __restrict__ pairs, const int* __restrict__ smat,
                             int* __restrict__ col, int* __restrict__ rp,
                             float* __restrict__ norms) {
    __shared__ int srt[SCAP];
    __shared__ int lcnt[BROWS];
    __shared__ int roff[BROWS];
    __shared__ int lcur[BROWS];
    __shared__ int ssum[1024];
    int k = blockIdx.x;
    int t = threadIdx.x;
    int base = smat[(size_t)k * NB];
    int end  = (k + 1 < NBUCK) ? smat[(size_t)(k + 1) * NB] : CO_TOT;
    int nb = end - base;
    lcnt[t] = 0;
    lcur[t] = 0;
    __syncthreads();
    for (int i = base + t; i < end; i += 1024)
        atomicAdd(&lcnt[pairs[i] & (BROWS - 1)], 1);
    __syncthreads();
    int a0 = lcnt[t];
    ssum[t] = a0;
    __syncthreads();
    for (int off = 1; off < 1024; off <<= 1) {
        int u = (t >= off) ? ssum[t - off] : 0;
        __syncthreads();
        ssum[t] += u;
        __syncthreads();
    }
    int gex = ssum[t] - a0;
    roff[t] = gex;
    int row = k * BROWS + t;
    rp[row] = base + gex;
    norms[row] = rsqrtf((float)(a0 + 1));           // +1 self-loop
    if (k == 0 && t == 0) rp[NS_TOT] = CO_TOT;
    __syncthreads();
    if (nb <= SCAP) {
        for (int i = base + t; i < end; i += 1024) {
            unsigned p = pairs[i];
            int rl = p & (BROWS - 1);
            int pos = roff[rl] + atomicAdd(&lcur[rl], 1);
            srt[pos] = (int)(p >> 10);
        }
        __syncthreads();
        for (int j = t; j < nb; j += 1024)
            col[base + j] = srt[j];
    } else {
        for (int i = base + t; i < end; i += 1024) {
            unsigned p = pairs[i];
            int rl = p & (BROWS - 1);
            int pos = base + roff[rl] + atomicAdd(&lcur[rl], 1);
            col[pos] = (int)(p >> 10);
        }
    }
}

// ---- global scan ------------------------------------------------------

__global__ void scan1_kernel(const int* __restrict__ cnt, int* __restrict__ rp,
                             int* __restrict__ part, int n) {
    __shared__ int sh[1024];
    int t = threadIdx.x;
    int i = blockIdx.x * 1024 + t;
    int v = (i < n) ? cnt[i] : 0;
    sh[t] = v;
    __syncthreads();
    for (int off = 1; off < 1024; off <<= 1) {
        int u = (t >= off) ? sh[t - off] : 0;
        __syncthreads();
        sh[t] += u;
        __syncthreads();
    }
    if (i < n) rp[i] = sh[t] - v;
    if (t == 1023) part[blockIdx.x] = sh[1023];
}

__global__ void scan2_kernel(int* part, int m) {
    __shared__ int sh[256];
    __shared__ int carry;
    int t = threadIdx.x;
    if (t == 0) carry = 0;
    __syncthreads();
    for (int base = 0; base < m; base += 256) {
        int i = base + t;
        int v = (i < m) ? part[i] : 0;
        sh[t] = v;
        __syncthreads();
        for (int off = 1; off < 256; off <<= 1) {
            int u = (t >= off) ? sh[t - off] : 0;
            __syncthreads();
            sh[t] += u;
            __syncthreads();
        }
        if (i < m) part[i] = sh[t] - v + carry;
        __syncthreads();
        if (t == 255) carry += sh[255];
        __syncthreads();
    }
}

__global__ void scan3_kernel(int* __restrict__ rp, const int* __restrict__ part, int n) {
    int i = blockIdx.x * blockDim.x + threadIdx.x;
    if (i < n) rp[i] += part[i >> 10];
}

// ---- bf16 helpers ------------------------------------------------------

__device__ inline unsigned bf16rne(float f) {
    unsigned u = __float_as_uint(f);
    return (u + 0x7fffu + ((u >> 16) & 1u)) >> 16;
}
__device__ inline float bfl(unsigned u) { return __uint_as_float(u << 16); }
__device__ inline float bfh(unsigned u) { return __uint_as_float(u & 0xffff0000u); }

// ---- xsb prep + out init ----------------------------------------------

__global__ void xsb_kernel(const float* __restrict__ x, const float* __restrict__ nrm,
                           uint2* __restrict__ xsb, int n) {
    int r = blockIdx.x * blockDim.x + threadIdx.x;
    if (r >= n) return;
    float nm = nrm[r];
    float4 v = *(const float4*)(x + (size_t)r * 4);
    xsb[r] = make_uint2(bf16rne(v.x * nm) | (bf16rne(v.y * nm) << 16),
                        bf16rne(v.z * nm) | (bf16rne(v.w * nm) << 16));
}

__global__ void init_out_kernel(float* out, const float* __restrict__ lin_b) {
    int i = threadIdx.x;
    if (i < GG) out[i] = lin_b[0];
}

// ---- conv schedule (26 steps = 2 passes x 13), R13-R17-verified --------

struct Step {
    int buf, ns, bsel, gbase, rlo, wh;
    int e0on, e0n, e0h, e0w, e0r;
    int e1on, e1n, e1h, e1w, e1r;
};

__device__ __constant__ Step SCHED[26] = {
    // pass 0
    {SA_O, NS_IN(0), 0, 0, 0, 0,        1, NS_F(0), F0_O, 1, 0,              1, NS_B(0), B0_O, 2, 1},
    {F0_O, NS_F(0), 1, 0, NLK, 0,       1, NS_IN(1), SB_O, 0, 0,             0,0,0,0,0},
    {SB_O, NS_IN(1), 0, NLK, 0, 0,      1, NS_F(1), F1_O, 1, 0,              1, NS_B(1), B1_O, 2, 1},
    {F1_O, NS_F(1), 1, NLK, NLK, 0,     1, NS_IN(2), SC_O, 0, 0,             0,0,0,0,0},
    {SC_O, NS_IN(2), 0, 2*NLK, 0, 0,    1, NS_F(2), F2_O, 1, 0,              1, NS_B(2), B2_O, 2, 1},
    {F2_O, NS_F(2), 1, 2*NLK, NLK, 0,   1, NS_IN(3), SA_O, 0, 0,             0,0,0,0,0},
    {SA_O, NS_IN(3), 0, 3*NLK, 0, 0,    1, NS_B(2)+NLK, B2_O+SLOT_U, 2, 1,   1, NS_F(2)+NLK, F2_O+SLOT_U, 1, 1},
    {B2_O, NS_B(2), 2, 2*NLK, 0, 0,     1, NS_IN(2), SC_O, 0, 0,             0,0,0,0,0},
    {SC_O, NS_IN(2), 0, 2*NLK, 0, 0,    1, NS_B(1)+NLK, B1_O+SLOT_U, 2, 0,   1, NS_F(1)+NLK, F1_O+SLOT_U, 1, 1},
    {B1_O, NS_B(1), 2, NLK, 0, 0,       1, NS_IN(1), SB_O, 0, 0,             0,0,0,0,0},
    {SB_O, NS_IN(1), 0, NLK, 0, 0,      1, NS_B(0)+NLK, B0_O+SLOT_U, 2, 0,   1, NS_F(0)+NLK, F0_O+SLOT_U, 1, 1},
    {B0_O, NS_B(0), 2, 0, 0, 0,         1, NS_IN(0), SD_O, 0, 0,             0,0,0,0,0},
    {SD_O, NS_IN(0), 0, 0, 0, 0,        1, NS_IN(0), SA_O, 0, 1,             0,0,0,0,0},
    // pass 1
    {SA_O, NS_IN(0), 0, 0, 0, 0,        1, NS_F(0), F0_O, 1, 0,              1, NS_B(0), B0_O, 2, 1},
    {F0_O, NS_F(0), 1, 0, NLK, 0,       1, NS_IN(1), SB_O, 0, 0,             0,0,0,0,0},
    {SB_O, NS_IN(1), 0, NLK, 0, 0,      1, NS_F(1), F1_O, 1, 0,              1, NS_B(1), B1_O, 2, 1},
    {F1_O, NS_F(1), 1, NLK, NLK, 0,     1, NS_IN(2), SC_O, 0, 0,             0,0,0,0,0},
    {SC_O, NS_IN(2), 0, 2*NLK, 0, 0,    1, NS_F(2), F2_O, 1, 0,              1, NS_B(2), B2_O, 2, 1},
    {F2_O, NS_F(2), 1, 2*NLK, NLK, 0,   1, NS_IN(3), SA_O, 0, 0,             0,0,0,0,0},
    {SA_O, NS_IN(3), 0, 3*NLK, 0, 1,    1, NS_B(2)+NLK, B2_O+SLOT_U, 2, 1,   0,0,0,0,0},
    {B2_O, NS_B(2), 2, 2*NLK, 0, 0,     1, NS_IN(2), SC_O, 0, 0,             0,0,0,0,0},
    {SC_O, NS_IN(2), 0, 2*NLK, 0, 1,    1, NS_B(1)+NLK, B1_O+SLOT_U, 2, 0,   0,0,0,0,0},
    {B1_O, NS_B(1), 2, NLK, 0, 0,       1, NS_IN(1), SB_O, 0, 0,             0,0,0,0,0},
    {SB_O, NS_IN(1), 0, NLK, 0, 1,      1, NS_B(0)+NLK, B0_O+SLOT_U, 2, 0,   0,0,0,0,0},
    {B0_O, NS_B(0), 2, 0, 0, 0,         1, NS_IN(0), SD_O, 0, 0,             0,0,0,0,0},
    {SD_O, NS_IN(0), 0, 0, 0, 1,        0,0,0,0,0,                           0,0,0,0,0},
};

// ---- cooperative mega-kernel: up conv + 26 convs + pool ----------------
// 256 blocks x 1024 thr, 1 block/CU: co-residency guaranteed.

__global__ void __launch_bounds__(MTHR, 4)
mega_kernel(const int* __restrict__ rp, const int* __restrict__ col,
            unsigned* __restrict__ hsbp, const float* __restrict__ norms,
            float* __restrict__ h, const float* __restrict__ stat,
            const uint2* __restrict__ xsb,
            const float* __restrict__ W_in, const float* __restrict__ b_in,
            const float* __restrict__ W_f, const float* __restrict__ b_f,
            const float* __restrict__ W_b, const float* __restrict__ b_b,
            const float* __restrict__ W_up, const float* __restrict__ b_up,
            const int* __restrict__ gids, const float* __restrict__ lin_W,
            float* __restrict__ out) {
    cg::grid_group grid = cg::this_grid();
    __shared__ float WA[1280];
    __shared__ float WB[1280];
    __shared__ float Wu[128];
    __shared__ float bu[32];
    __shared__ float rowbuf[128][41];
    __shared__ float part[GG];
    int t = threadIdx.x;
    int j = t & 7;
    int lrow = t >> 3;
    int hw = j * 2;
    int q = j * 4;

    // ======== phase U: up conv (pull4 + 4x32 mm + per-layer emission) ========
    for (int i = t; i < 128; i += MTHR) Wu[i] = W_up[i];
    if (t < 32) bu[t] = b_up[t];
    for (int i = t; i < 1280; i += MTHR) { WA[i] = W_in[i]; WB[i] = W_f[i]; }
    __syncthreads();
    for (int it = 0; it < 8; it++) {
        int tid = it * (MBLK * MTHR) + blockIdx.x * MTHR + t;
        int g = tid >> 3;
        int ea = rp[g], eb = rp[g + 1];
        float a0 = 0.f, a1 = 0.f, a2 = 0.f, a3 = 0.f;
        int e = ea + j;
        for (; e + 8 < eb; e += 16) {
            uint2 v0 = xsb[col[e]];
            uint2 v1 = xsb[col[e + 8]];
            a0 += bfl(v0.x) + bfl(v1.x); a1 += bfh(v0.x) + bfh(v1.x);
            a2 += bfl(v0.y) + bfl(v1.y); a3 += bfh(v0.y) + bfh(v1.y);
        }
        if (e < eb) {
            uint2 v = xsb[col[e]];
            a0 += bfl(v.x); a1 += bfh(v.x); a2 += bfl(v.y); a3 += bfh(v.y);
        }
#pragma unroll
        for (int m = 1; m < 8; m <<= 1) {
            a0 += __shfl_xor(a0, m);
            a1 += __shfl_xor(a1, m);
            a2 += __shfl_xor(a2, m);
            a3 += __shfl_xor(a3, m);
        }
        uint2 sv = xsb[g];
        a0 += bfl(sv.x); a1 += bfh(sv.x); a2 += bfl(sv.y); a3 += bfh(sv.y);
        float nm = norms[g];
#pragma unroll
        for (int d = 0; d < 4; d++) {
            float s = a0 * Wu[q + d] + a1 * Wu[32 + q + d] + a2 * Wu[64 + q + d] + a3 * Wu[96 + q + d];
            rowbuf[lrow][q + d] = fmaf(s, nm, bu[q + d]);
        }
        rowbuf[lrow][32 + j] = stat[(size_t)g * 8 + j];
        __syncthreads();
        int l = g >> 16;
        const float* W = (l == 0) ? WA : WB;
        int noff = (l == 0) ? NS_IN(0) : (l == 1) ? NS_F(0) : (l == 2) ? (NS_F(1) - NLK) : (NS_F(2) - 2 * NLK);
        int hoff = (l == 0) ? SA_O : (l == 1) ? F0_O : (l == 2) ? (F1_O - SLOT_U) : (F2_O - 2 * SLOT_U);
        float nmc = norms[noff + g];
        float r0 = 0, r1 = 0, r2 = 0, r3 = 0;
#pragma unroll
        for (int k = 0; k < 40; k++) {
            float v = rowbuf[lrow][k];
            const float* Wp = &W[k * 32 + q];
            r0 = fmaf(v, Wp[0], r0); r1 = fmaf(v, Wp[1], r1);
            r2 = fmaf(v, Wp[2], r2); r3 = fmaf(v, Wp[3], r3);
        }
        unsigned u0 = bf16rne(r0 * nmc) | (bf16rne(r1 * nmc) << 16);
        unsigned u1 = bf16rne(r2 * nmc) | (bf16rne(r3 * nmc) << 16);
        *(uint2*)(hsbp + (size_t)hoff + (size_t)g * 16 + hw) = make_uint2(u0, u1);
        __syncthreads();
    }
    __threadfence();
    grid.sync();

    // ======== 26 conv phases ========
    for (int s = 0; s < 26; s++) {
        Step S = SCHED[s];
        const float* bias = (S.bsel == 0) ? b_in : (S.bsel == 1) ? b_f : b_b;
        if (S.e0on) {
            const float* Wt = (S.e0w == 0) ? W_in : (S.e0w == 1) ? W_f : W_b;
            for (int i = t; i < 1280; i += MTHR) WA[i] = Wt[i];
        }
        if (S.e1on) {
            const float* Wt = (S.e1w == 0) ? W_in : (S.e1w == 1) ? W_f : W_b;
            for (int i = t; i < 1280; i += MTHR) WB[i] = Wt[i];
        }
        __syncthreads();
        const unsigned* hin = hsbp + S.buf;
        for (int it = 0; it < 2; it++) {
            int tid = it * (MBLK * MTHR) + blockIdx.x * MTHR + t;
            int rr = tid >> 3;
            int r = S.rlo + rr;
            int ea = rp[S.ns + r], eb = rp[S.ns + r + 1];
            uint2 sv = *(const uint2*)(hin + (size_t)r * 16 + hw);
            float a0 = bfl(sv.x), a1 = bfh(sv.x), a2 = bfl(sv.y), a3 = bfh(sv.y);
            int e = ea;
            for (; e + 2 <= eb; e += 2) {
                int s0 = col[e];
                int s1 = col[e + 1];
                uint2 v0 = *(const uint2*)(hin + (size_t)s0 * 16 + hw);
                uint2 v1 = *(const uint2*)(hin + (size_t)s1 * 16 + hw);
                a0 += bfl(v0.x) + bfl(v1.x); a1 += bfh(v0.x) + bfh(v1.x);
                a2 += bfl(v0.y) + bfl(v1.y); a3 += bfh(v0.y) + bfh(v1.y);
            }
            if (e < eb) {
                int s0 = col[e];
                uint2 v = *(const uint2*)(hin + (size_t)s0 * 16 + hw);
                a0 += bfl(v.x); a1 += bfh(v.x); a2 += bfl(v.y); a3 += bfh(v.y);
            }
            float nm = norms[S.ns + r];
            float4 bv = *(const float4*)(bias + q);
            float o0 = fmaf(a0, nm, bv.x), o1 = fmaf(a1, nm, bv.y);
            float o2 = fmaf(a2, nm, bv.z), o3 = fmaf(a3, nm, bv.w);
            if (S.wh)
                *(float4*)(h + (size_t)(S.gbase + S.rlo + rr) * DYNF + q) = make_float4(o0, o1, o2, o3);
            rowbuf[lrow][q] = o0; rowbuf[lrow][q + 1] = o1;
            rowbuf[lrow][q + 2] = o2; rowbuf[lrow][q + 3] = o3;
            rowbuf[lrow][32 + j] = stat[(size_t)(S.gbase + S.rlo + rr) * 8 + j];
            __syncthreads();
            if (S.e0on) {
                float nmc = norms[S.e0n + rr];
                float r0 = 0, r1 = 0, r2 = 0, r3 = 0;
#pragma unroll
                for (int k = 0; k < 40; k++) {
                    float v = rowbuf[lrow][k];
                    if (k < 32 && S.e0r) v = fmaxf(v, 0.f);
                    const float* Wp = &WA[k * 32 + q];
                    r0 = fmaf(v, Wp[0], r0); r1 = fmaf(v, Wp[1], r1);
                    r2 = fmaf(v, Wp[2], r2); r3 = fmaf(v, Wp[3], r3);
                }
                unsigned u0 = bf16rne(r0 * nmc) | (bf16rne(r1 * nmc) << 16);
                unsigned u1 = bf16rne(r2 * nmc) | (bf16rne(r3 * nmc) << 16);
                *(uint2*)(hsbp + (size_t)S.e0h + (size_t)rr * 16 + hw) = make_uint2(u0, u1);
            }
            if (S.e1on) {
                float nmc = norms[S.e1n + rr];
                float r0 = 0, r1 = 0, r2 = 0, r3 = 0;
#pragma unroll
                for (int k = 0; k < 40; k++) {
                    float v = rowbuf[lrow][k];
                    if (k < 32 && S.e1r) v = fmaxf(v, 0.f);
                    const float* Wp = &WB[k * 32 + q];
                    r0 = fmaf(v, Wp[0], r0); r1 = fmaf(v, Wp[1], r1);
                    r2 = fmaf(v, Wp[2], r2); r3 = fmaf(v, Wp[3], r3);
                }
                unsigned u0 = bf16rne(r0 * nmc) | (bf16rne(r1 * nmc) << 16);
                unsigned u1 = bf16rne(r2 * nmc) | (bf16rne(r3 * nmc) << 16);
                *(uint2*)(hsbp + (size_t)S.e1h + (size_t)rr * 16 + hw) = make_uint2(u0, u1);
            }
            __syncthreads();
        }
        __threadfence();
        grid.sync();
    }

    // ======== pool phase (final relu fused) ========
    if (t < GG) part[t] = 0.f;
    __syncthreads();
    int r = blockIdx.x * MTHR + t;                  // exactly NN threads
    float dotv = 0.f;
    const float4* hp = (const float4*)(h + (size_t)r * DYNF);
#pragma unroll
    for (int qq = 0; qq < 8; qq++) {
        float4 v = hp[qq];
        dotv += fmaxf(v.x, 0.f) * lin_W[qq * 4 + 0] + fmaxf(v.y, 0.f) * lin_W[qq * 4 + 1] +
                fmaxf(v.z, 0.f) * lin_W[qq * 4 + 2] + fmaxf(v.w, 0.f) * lin_W[qq * 4 + 3];
    }
    atomicAdd(&part[gids[r]], dotv);
    __syncthreads();
    if (t < GG) unsafeAtomicAdd(&out[t], part[t]);
}

// ---- R17 fallback kernels (pull + pack-emission path) ------------------

struct EmitArg {
    const float* nrm;
    unsigned*    hsb;
    const float* W;
    int relu;
    int on;
};

__global__ void pull_emit_kernel(const int* __restrict__ rp, const int* __restrict__ col,
                                 const unsigned* __restrict__ hsb_in, const float* __restrict__ nrm,
                                 const float* __restrict__ b, float* __restrict__ out,
                                 const float* __restrict__ stat_p, int row_lo, int write_h,
                                 EmitArg em0, EmitArg em1) {
    __shared__ float W0[1280];
    __shared__ float W1[1280];
    __shared__ float rowbuf[32][41];
    int t = threadIdx.x;
    if (em0.on) for (int i = t; i < 1280; i += 256) W0[i] = em0.W[i];
    if (em1.on) for (int i = t; i < 1280; i += 256) W1[i] = em1.W[i];
    int tid = blockIdx.x * 256 + t;
    int rr = tid >> 3;
    int r = row_lo + rr;
    int j = tid & 7;
    int hw = j * 2;
    int ea = rp[r], eb = rp[r + 1];
    uint2 sv = *(const uint2*)(hsb_in + (size_t)r * 16 + hw);
    float a0 = bfl(sv.x), a1 = bfh(sv.x), a2 = bfl(sv.y), a3 = bfh(sv.y);
    int e = ea;
    for (; e + 2 <= eb; e += 2) {
        int s0 = col[e];
        int s1 = col[e + 1];
        uint2 v0 = *(const uint2*)(hsb_in + (size_t)s0 * 16 + hw);
        uint2 v1 = *(const uint2*)(hsb_in + (size_t)s1 * 16 + hw);
        a0 += bfl(v0.x) + bfl(v1.x); a1 += bfh(v0.x) + bfh(v1.x);
        a2 += bfl(v0.y) + bfl(v1.y); a3 += bfh(v0.y) + bfh(v1.y);
    }
    if (e < eb) {
        int s = col[e];
        uint2 v = *(const uint2*)(hsb_in + (size_t)s * 16 + hw);
        a0 += bfl(v.x); a1 += bfh(v.x); a2 += bfl(v.y); a3 += bfh(v.y);
    }
    float nm = nrm[r];
    int q = j * 4;
    float4 bv = *(const float4*)(b + q);
    float o0 = fmaf(a0, nm, bv.x), o1 = fmaf(a1, nm, bv.y);
    float o2 = fmaf(a2, nm, bv.z), o3 = fmaf(a3, nm, bv.w);
    if (write_h)
        *(float4*)(out + (size_t)r * DYNF + q) = make_float4(o0, o1, o2, o3);
    if (!em0.on && !em1.on) return;
    int lrow = t >> 3;
    rowbuf[lrow][q] = o0; rowbuf[lrow][q + 1] = o1;
    rowbuf[lrow][q + 2] = o2; rowbuf[lrow][q + 3] = o3;
    rowbuf[lrow][32 + j] = stat_p[(size_t)rr * 8 + j];
    __syncthreads();
    if (em0.on) {
        float nmc = em0.nrm[rr];
        float r0 = 0, r1 = 0, r2 = 0, r3 = 0;
#pragma unroll
        for (int k = 0; k < 40; k++) {
            float v = rowbuf[lrow][k];
            if (k < 32 && em0.relu) v = fmaxf(v, 0.f);
            const float* Wp = &W0[k * 32 + q];
            r0 = fmaf(v, Wp[0], r0); r1 = fmaf(v, Wp[1], r1);
            r2 = fmaf(v, Wp[2], r2); r3 = fmaf(v, Wp[3], r3);
        }
        unsigned u0 = bf16rne(r0 * nmc) | (bf16rne(r1 * nmc) << 16);
        unsigned u1 = bf16rne(r2 * nmc) | (bf16rne(r3 * nmc) << 16);
        *(uint2*)(em0.hsb + (size_t)rr * 16 + hw) = make_uint2(u0, u1);
    }
    if (em1.on) {
        float nmc = em1.nrm[rr];
        float r0 = 0, r1 = 0, r2 = 0, r3 = 0;
#pragma unroll
        for (int k = 0; k < 40; k++) {
            float v = rowbuf[lrow][k];
            if (k < 32 && em1.relu) v = fmaxf(v, 0.f);
            const float* Wp = &W1[k * 32 + q];
            r0 = fmaf(v, Wp[0], r0); r1 = fmaf(v, Wp[1], r1);
            r2 = fmaf(v, Wp[2], r2); r3 = fmaf(v, Wp[3], r3);
        }
        unsigned u0 = bf16rne(r0 * nmc) | (bf16rne(r1 * nmc) << 16);
        unsigned u1 = bf16rne(r2 * nmc) | (bf16rne(r3 * nmc) << 16);
        *(uint2*)(em1.hsb + (size_t)rr * 16 + hw) = make_uint2(u0, u1);
    }
}

struct UpEmit {
    const float* n0; const float* n1; const float* n2; const float* n3;
    unsigned* h0; unsigned* h1; unsigned* h2; unsigned* h3;
};

__global__ void pull4mm_emit_kernel(const int* __restrict__ rp0, const int* __restrict__ col,
                                    const uint2* __restrict__ xsb, const float* __restrict__ Wup,
                                    const float* __restrict__ nrm, const float* __restrict__ bup,
                                    const float* __restrict__ Win, const float* __restrict__ Wf,
                                    const float* __restrict__ stat, UpEmit ue) {
    __shared__ float Ws[128];
    __shared__ float bs[32];
    __shared__ float Wa[1280];
    __shared__ float Wb[1280];
    __shared__ float rowbuf[32][41];
    int t = threadIdx.x;
    for (int i = t; i < 128; i += 256) Ws[i] = Wup[i];
    if (t < 32) bs[t] = bup[t];
    for (int i = t; i < 1280; i += 256) { Wa[i] = Win[i]; Wb[i] = Wf[i]; }
    __syncthreads();
    int tid = blockIdx.x * 256 + t;
    int g = tid >> 3;
    int j = t & 7;
    int ea = rp0[g], eb = rp0[g + 1];
    float a0 = 0.f, a1 = 0.f, a2 = 0.f, a3 = 0.f;
    int e = ea + j;
    for (; e + 8 < eb; e += 16) {
        uint2 v0 = xsb[col[e]];
        uint2 v1 = xsb[col[e + 8]];
        a0 += bfl(v0.x) + bfl(v1.x); a1 += bfh(v0.x) + bfh(v1.x);
        a2 += bfl(v0.y) + bfl(v1.y); a3 += bfh(v0.y) + bfh(v1.y);
    }
    if (e < eb) {
        uint2 v = xsb[col[e]];
        a0 += bfl(v.x); a1 += bfh(v.x); a2 += bfl(v.y); a3 += bfh(v.y);
    }
#pragma unroll
    for (int m = 1; m < 8; m <<= 1) {
        a0 += __shfl_xor(a0, m);
        a1 += __shfl_xor(a1, m);
        a2 += __shfl_xor(a2, m);
        a3 += __shfl_xor(a3, m);
    }
    uint2 sv = xsb[g];
    a0 += bfl(sv.x); a1 += bfh(sv.x); a2 += bfl(sv.y); a3 += bfh(sv.y);
    float nm = nrm[g];
    int q = j * 4;
    int lrow = t >> 3;
#pragma unroll
    for (int d = 0; d < 4; d++) {
        float s = a0 * Ws[q + d] + a1 * Ws[32 + q + d] + a2 * Ws[64 + q + d] + a3 * Ws[96 + q + d];
        rowbuf[lrow][q + d] = fmaf(s, nm, bs[q + d]);
    }
    rowbuf[lrow][32 + j] = stat[(size_t)g * 8 + j];
    __syncthreads();
    int l = g >> 16;
    const float* W = (l == 0) ? Wa : Wb;
    const float* nc = (l == 0) ? ue.n0 : (l == 1) ? ue.n1 : (l == 2) ? ue.n2 : ue.n3;
    unsigned* hb = (l == 0) ? ue.h0 : (l == 1) ? ue.h1 : (l == 2) ? ue.h2 : ue.h3;
    float nmc = nc[g];
    float r0 = 0, r1 = 0, r2 = 0, r3 = 0;
#pragma unroll
    for (int k = 0; k < 40; k++) {
        float v = rowbuf[lrow][k];
        const float* Wp = &W[k * 32 + q];
        r0 = fmaf(v, Wp[0], r0); r1 = fmaf(v, Wp[1], r1);
        r2 = fmaf(v, Wp[2], r2); r3 = fmaf(v, Wp[3], r3);
    }
    unsigned u0 = bf16rne(r0 * nmc) | (bf16rne(r1 * nmc) << 16);
    unsigned u1 = bf16rne(r2 * nmc) | (bf16rne(r3 * nmc) << 16);
    *(uint2*)(hb + (size_t)g * 16 + j * 2) = make_uint2(u0, u1);
}

__global__ void pool_kernel(const float* __restrict__ h, const int* __restrict__ gids,
                            const float* __restrict__ linW, float* out) {
    __shared__ float part[GG];
    int t = threadIdx.x;
    if (t < GG) part[t] = 0.f;
    __syncthreads();
    int r = blockIdx.x * blockDim.x + t;
    float dotv = 0.f;
    const float4* hp = (const float4*)(h + (size_t)r * DYNF);
#pragma unroll
    for (int q = 0; q < 8; q++) {
        float4 v = hp[q];
        dotv += fmaxf(v.x, 0.f) * linW[q * 4 + 0] + fmaxf(v.y, 0.f) * linW[q * 4 + 1] +
                fmaxf(v.z, 0.f) * linW[q * 4 + 2] + fmaxf(v.w, 0.f) * linW[q * 4 + 3];
    }
    atomicAdd(&part[gids[r]], dotv);
    __syncthreads();
    if (t < GG) unsafeAtomicAdd(&out[t], part[t]);
}

// ------------------------------------------------------------------------

extern "C" void kernel_launch(void* const* d_in, const int* in_sizes, int n_in,
                              void* d_out, int out_size, void* d_ws, size_t ws_size,
                              hipStream_t stream) {
    const float* x     = (const float*)d_in[0];
    const float* stat  = (const float*)d_in[1];
    const int*   e_up  = (const int*)d_in[2];
    const int*   e_in  = (const int*)d_in[3];
    const int*   e_f   = (const int*)d_in[4];
    const int*   e_b   = (const int*)d_in[5];
    const int*   gids  = (const int*)d_in[6];
    const float* W_up  = (const float*)d_in[7];
    const float* b_up  = (const float*)d_in[8];
    const float* W_in  = (const float*)d_in[9];
    const float* b_in  = (const float*)d_in[10];
    const float* W_f   = (const float*)d_in[11];
    const float* b_f   = (const float*)d_in[12];
    const float* W_b   = (const float*)d_in[13];
    const float* b_b   = (const float*)d_in[14];
    const float* lin_W = (const float*)d_in[15];
    const float* lin_b = (const float*)d_in[16];
    float* out = (float*)d_out;

    // ---- workspace carve (~172 MB peak) ----
    float*    norms = (float*)d_ws;                              // NS_TOT
    int*      rp    = (int*)(norms + NS_TOT);                    // NS_TOT+1
    int*      col   = rp + NS_TOT + 1;                           // CO_TOT
    unsigned* H0    = (unsigned*)(col + CO_TOT);                 // conv region base
    float*    h     = (float*)H0;                                // NN*32 f32
    unsigned* hsbp  = H0 + (size_t)NN * DYNF;                    // pack pool: 16*NLK rows *16 u32
    uint2*    xsb   = (uint2*)(hsbp + (size_t)16 * NLK * 16);    // NN uint2 (dedicated)
    unsigned* pairs = H0;                                        // build alias (CO_TOT u32)
    int*      hmat  = (int*)(H0 + CO_TOT);                       // HM
    int*      smat  = hmat + HM;                                 // HM
    int*      part  = smat + HM;                                 // >= 560

    unsigned* SA  = hsbp + (size_t)0  * SLOT_U;
    unsigned* SB  = hsbp + (size_t)1  * SLOT_U;
    unsigned* SC  = hsbp + (size_t)2  * SLOT_U;
    unsigned* SD  = hsbp + (size_t)3  * SLOT_U;
    unsigned* F0b = hsbp + (size_t)4  * SLOT_U;
    unsigned* F1b = hsbp + (size_t)6  * SLOT_U;
    unsigned* F2b = hsbp + (size_t)8  * SLOT_U;
    unsigned* B0b = hsbp + (size_t)10 * SLOT_U;
    unsigned* B1b = hsbp + (size_t)12 * SLOT_U;
    unsigned* B2b = hsbp + (size_t)14 * SLOT_U;

    // ---- build: zero-global-atomic radix partition + LDS-staged passes ----
    hist_part_kernel<<<NB, 1024, 0, stream>>>(e_up, e_in, e_f, e_b, hmat);
    scan1_kernel<<<HM / 1024, 1024, 0, stream>>>(hmat, smat, part, HM);
    scan2_kernel<<<1, 256, 0, stream>>>(part, HM / 1024);
    scan3_kernel<<<cdiv(HM, 256), 256, 0, stream>>>(smat, part, HM);
    scatter_part_kernel<<<NB, 1024, 0, stream>>>(e_up, e_in, e_f, e_b, hmat, smat, pairs);
    group_kernel<<<NBUCK, 1024, 0, stream>>>(pairs, smat, col, rp, norms);

    // ---- prep: xsb + out init ----
    xsb_kernel<<<cdiv(NN, 256), 256, 0, stream>>>(x, norms + NS_UP, xsb, NN);
    init_out_kernel<<<1, 64, 0, stream>>>(out, lin_b);

    // ---- cooperative-capability check (stream-free, deterministic) ----
    int coopAttr = 0, dev = 0, maxB = 0;
    hipGetDevice(&dev);
    hipDeviceGetAttribute(&coopAttr, hipDeviceAttributeCooperativeLaunch, dev);
    hipOccupancyMaxActiveBlocksPerMultiprocessor(&maxB, mega_kernel, MTHR, 0);
    bool use_coop = (coopAttr != 0) && (maxB >= 1);

    if (use_coop) {
        const int* a_rp = rp; const int* a_col = col;
        unsigned* a_hsbp = hsbp; const float* a_norms = norms;
        float* a_h = h; const float* a_stat = stat;
        const uint2* a_xsb = xsb;
        const float* a_Win = W_in; const float* a_bin = b_in;
        const float* a_Wf = W_f; const float* a_bf = b_f;
        const float* a_Wb = W_b; const float* a_bb = b_b;
        const float* a_Wup = W_up; const float* a_bup = b_up;
        const int* a_gids = gids; const float* a_linW = lin_W;
        float* a_out = out;
        void* args[] = { &a_rp, &a_col, &a_hsbp, &a_norms, &a_h, &a_stat, &a_xsb,
                         &a_Win, &a_bin, &a_Wf, &a_bf, &a_Wb, &a_bb, &a_Wup, &a_bup,
                         &a_gids, &a_linW, &a_out };
        hipLaunchCooperativeKernel((void*)mega_kernel, dim3(MBLK), dim3(MTHR),
                                   args, 0, stream);
        return;
    }

    // ---- fallback: R17 multi-kernel path ----
    UpEmit ue;
    ue.n0 = norms + NS_IN(0);
    ue.n1 = norms + NS_F(0);
    ue.n2 = norms + NS_F(1) - NLK;
    ue.n3 = norms + NS_F(2) - 2 * NLK;
    ue.h0 = SA;
    ue.h1 = F0b;
    ue.h2 = F1b - (size_t)SLOT_U;
    ue.h3 = F2b - (size_t)2 * SLOT_U;
    pull4mm_emit_kernel<<<(NN * 8) / 256, 256, 0, stream>>>(rp + NS_UP, col, xsb, W_up,
                                                            norms + NS_UP, b_up, W_in, W_f, stat, ue);

    auto EM = [&](const float* n, unsigned* hb, const float* W, int rl) {
        EmitArg e; e.nrm = n; e.hsb = hb; e.W = W; e.relu = rl; e.on = 1; return e;
    };
    EmitArg OFF; OFF.nrm = nullptr; OFF.hsb = nullptr; OFF.W = nullptr; OFF.relu = 0; OFF.on = 0;

    auto P = [&](unsigned* buf, int ns, const float* bias, int gbase, int row_lo,
                 int wh, EmitArg a, EmitArg c) {
        pull_emit_kernel<<<(NLK * 8) / 256, 256, 0, stream>>>(
            rp + ns, col, buf, norms + ns, bias, h + (size_t)gbase * DYNF,
            stat + (size_t)(gbase + row_lo) * STATF, row_lo, wh, a, c);
    };

    for (int p = 0; p < 2; p++) {
        P(SA, NS_IN(0), b_in, 0, 0, 0,
          EM(norms + NS_F(0), F0b, W_f, 0), EM(norms + NS_B(0), B0b, W_b, 1));
        P(F0b, NS_F(0), b_f, 0, NLK, 0,
          EM(norms + NS_IN(1), SB, W_in, 0), OFF);
        P(SB, NS_IN(1), b_in, NLK, 0, 0,
          EM(norms + NS_F(1), F1b, W_f, 0), EM(norms + NS_B(1), B1b, W_b, 1));
        P(F1b, NS_F(1), b_f, NLK, NLK, 0,
          EM(norms + NS_IN(2), SC, W_in, 0), OFF);
        P(SC, NS_IN(2), b_in, 2 * NLK, 0, 0,
          EM(norms + NS_F(2), F2b, W_f, 0), EM(norms + NS_B(2), B2b, W_b, 1));
        P(F2b, NS_F(2), b_f, 2 * NLK, NLK, 0,
          EM(norms + NS_IN(3), SA, W_in, 0), OFF);
        P(SA, NS_IN(3), b_in, 3 * NLK, 0, (p == 1),
          EM(norms + NS_B(2) + NLK, B2b + (size_t)SLOT_U, W_b, 1),
          p == 0 ? EM(norms + NS_F(2) + NLK, F2b + (size_t)SLOT_U, W_f, 1) : OFF);
        P(B2b, NS_B(2), b_b, 2 * NLK, 0, 0,
          EM(norms + NS_IN(2), SC, W_in, 0), OFF);
        P(SC, NS_IN(2), b_in, 2 * NLK, 0, (p == 1),
          EM(norms + NS_B(1) + NLK, B1b + (size_t)SLOT_U, W_b, 0),
          p == 0 ? EM(norms + NS_F(1) + NLK, F1b + (size_t)SLOT_U, W_f, 1) : OFF);
        P(B1b, NS_B(1), b_b, NLK, 0, 0,
          EM(norms + NS_IN(1), SB, W_in, 0), OFF);
        P(SB, NS_IN(1), b_in, NLK, 0, (p == 1),
          EM(norms + NS_B(0) + NLK, B0b + (size_t)SLOT_U, W_b, 0),
          p == 0 ? EM(norms + NS_F(0) + NLK, F0b + (size_t)SLOT_U, W_f, 1) : OFF);
        P(B0b, NS_B(0), b_b, 0, 0, 0,
          EM(norms + NS_IN(0), SD, W_in, 0), OFF);
        P(SD, NS_IN(0), b_in, 0, 0, (p == 1),
          p == 0 ? EM(norms + NS_IN(0), SA, W_in, 1) : OFF, OFF);
    }

    pool_kernel<<<NN / 256, 256, 0, stream>>>(h, gids, lin_W, out);
}

// Round 20
// 807.290 us; speedup vs baseline: 1.0030x; 1.0030x over previous
//
#include <hip/hip_runtime.h>
#include <hip/hip_cooperative_groups.h>
namespace cg = cooperative_groups;

#define NLK 65536
#define NN (NLK * 4)        // 262144 nodes
#define DYNF 32
#define STATF 8
#define GG 64
#define EUP 4194304
#define EIN 1048576
#define EFB 1048576

// unified row space: [up: NN][inner: 4*NLK][fwd: 3*2NLK][bwd: 3*2NLK]
#define NS_UP    0
#define NS_IN(l) (NN + (l) * NLK)
#define NS_F(l)  (NN + 4 * NLK + (l) * 2 * NLK)
#define NS_B(l)  (NN + 10 * NLK + (l) * 2 * NLK)
#define NS_TOT   (NN + 16 * NLK)                    // 1,310,720
#define CO_TOT   (EUP + 4 * EIN + 6 * EFB)          // 14,680,064

#define CHUNK 32768                                 // edges per partition block
#define NB    (CO_TOT / CHUNK)                      // 448 partition blocks
#define BROWS 1024                                  // rows per bucket
#define NBUCK (NS_TOT / BROWS)                      // 1280 buckets
#define HM    (NBUCK * NB)                          // 573,440
#define SCAP  20480                                 // group LDS sort capacity

// pack-pool slot offsets (u32 units)
#define SLOT_U (NLK * 16)
#define SA_O 0
#define SB_O (1 * SLOT_U)
#define SC_O (2 * SLOT_U)
#define SD_O (3 * SLOT_U)
#define F0_O (4 * SLOT_U)
#define F1_O (6 * SLOT_U)
#define F2_O (8 * SLOT_U)
#define B0_O (10 * SLOT_U)
#define B1_O (12 * SLOT_U)
#define B2_O (14 * SLOT_U)

#define MBLK 512                                    // mega grid: 2 blocks/CU (TLP restored)
#define MTHR 512

static inline int cdiv(long a, int b) { return (int)((a + b - 1) / b); }

// ---- which list does partition block b cover? --------------------------
__device__ inline void cdecode(int b, const int* e_up, const int* e_in,
                               const int* e_f, const int* e_b,
                               const int*& srcp, const int*& dstp, int& ns, int& e0) {
    if (b < EUP / CHUNK) { srcp = e_up; dstp = e_up + EUP; ns = NS_UP; e0 = b * CHUNK; return; }
    int t = b - EUP / CHUNK;
    int list = t >> 5;                               // 32 blocks per small list
    e0 = (t & 31) * CHUNK;
    if (list < 4) {
        srcp = e_in + (size_t)(2 * list) * EIN; dstp = srcp + EIN; ns = NS_IN(list);
    } else if (list < 7) {
        int l = list - 4;
        srcp = e_f + (size_t)(2 * l) * EFB; dstp = srcp + EFB; ns = NS_F(l);
    } else {
        int l = list - 7;
        srcp = e_b + (size_t)(2 * l) * EFB; dstp = srcp + EFB; ns = NS_B(l);
    }
}

// ---- pass 1: per-block LDS bucket histogram (1024 threads) -------------
__global__ void hist_part_kernel(const int* __restrict__ e_up, const int* __restrict__ e_in,
                                 const int* __restrict__ e_f, const int* __restrict__ e_b,
                                 int* __restrict__ hmat) {
    __shared__ int lh[NBUCK];
    for (int k = threadIdx.x; k < NBUCK; k += 1024) lh[k] = 0;
    __syncthreads();
    const int *srcp, *dstp; int ns, e0;
    cdecode(blockIdx.x, e_up, e_in, e_f, e_b, srcp, dstp, ns, e0);
    for (int j = 0; j < CHUNK / 1024; j++) {
        int g = ns + dstp[e0 + j * 1024 + threadIdx.x];
        atomicAdd(&lh[g >> 10], 1);
    }
    __syncthreads();
    for (int k = threadIdx.x; k < NBUCK; k += 1024)
        hmat[(size_t)k * NB + blockIdx.x] = lh[k];
}

// ---- pass 2: LDS-staged bucket sort -> coalesced slice flush -----------
__global__ void scatter_part_kernel(const int* __restrict__ e_up, const int* __restrict__ e_in,
                                    const int* __restrict__ e_f, const int* __restrict__ e_b,
                                    const int* __restrict__ hmat, const int* __restrict__ smat,
                                    unsigned* __restrict__ pairs) {
    __shared__ unsigned srt[CHUNK];                 // 128 KB
    __shared__ int ls[NBUCK + 1];
    __shared__ int gbase[NBUCK];
    __shared__ int lcur[NBUCK];
    __shared__ int ssum[1024];
    int t = threadIdx.x;
    int b = blockIdx.x;
    const int *srcp, *dstp; int ns, e0;
    cdecode(b, e_up, e_in, e_f, e_b, srcp, dstp, ns, e0);
    int a0 = (2 * t < NBUCK) ? hmat[(size_t)(2 * t) * NB + b] : 0;
    int a1 = (2 * t + 1 < NBUCK) ? hmat[(size_t)(2 * t + 1) * NB + b] : 0;
    if (2 * t < NBUCK) gbase[2 * t] = smat[(size_t)(2 * t) * NB + b];
    if (2 * t + 1 < NBUCK) gbase[2 * t + 1] = smat[(size_t)(2 * t + 1) * NB + b];
    if (2 * t < NBUCK) lcur[2 * t] = 0;
    if (2 * t + 1 < NBUCK) lcur[2 * t + 1] = 0;
    int gsum = a0 + a1;
    ssum[t] = gsum;
    __syncthreads();
    for (int off = 1; off < 1024; off <<= 1) {
        int u = (t >= off) ? ssum[t - off] : 0;
        __syncthreads();
        ssum[t] += u;
        __syncthreads();
    }
    int run = ssum[t] - gsum;
    if (2 * t < NBUCK) ls[2 * t] = run;
    if (2 * t + 1 < NBUCK) ls[2 * t + 1] = run + a0;
    if (t == 0) ls[NBUCK] = CHUNK;                  // sentinel
    __syncthreads();
    for (int j = 0; j < CHUNK / 1024; j++) {
        int el = e0 + j * 1024 + t;
        int g = ns + dstp[el];
        int s = srcp[el];
        int k = g >> 10;
        int pos = ls[k] + atomicAdd(&lcur[k], 1);
        srt[pos] = ((unsigned)s << 10) | (unsigned)(g & (BROWS - 1));
    }
    __syncthreads();
    int wave = t >> 6;
    int lane = t & 63;
    for (int k = wave; k < NBUCK; k += 16) {
        int lo = ls[k];
        int n = ls[k + 1] - lo;
        int dst = gbase[k];
        for (int i = lane; i < n; i += 64)
            pairs[dst + i] = srt[lo + i];
    }
}

// ---- pass 3: per-bucket group; LDS-staged sort -> sequential col (1024 thr)
__global__ void group_kernel(const unsigned* __restrict__ pairs, const int* __restrict__ smat,
                             int* __restrict__ col, int* __restrict__ rp,
                             float* __restrict__ norms) {
    __shared__ int srt[SCAP];
    __shared__ int lcnt[BROWS];
    __shared__ int roff[BROWS];
    __shared__ int lcur[BROWS];
    __shared__ int ssum[1024];
    int k = blockIdx.x;
    int t = threadIdx.x;
    int base = smat[(size_t)k * NB];
    int end  = (k + 1 < NBUCK) ? smat[(size_t)(k + 1) * NB] : CO_TOT;
    int nb = end - base;
    lcnt[t] = 0;
    lcur[t] = 0;
    __syncthreads();
    for (int i = base + t; i < end; i += 1024)
        atomicAdd(&lcnt[pairs[i] & (BROWS - 1)], 1);
    __syncthreads();
    int a0 = lcnt[t];
    ssum[t] = a0;
    __syncthreads();
    for (int off = 1; off < 1024; off <<= 1) {
        int u = (t >= off) ? ssum[t - off] : 0;
        __syncthreads();
        ssum[t] += u;
        __syncthreads();
    }
    int gex = ssum[t] - a0;
    roff[t] = gex;
    int row = k * BROWS + t;
    rp[row] = base + gex;
    norms[row] = rsqrtf((float)(a0 + 1));           // +1 self-loop
    if (k == 0 && t == 0) rp[NS_TOT] = CO_TOT;
    __syncthreads();
    if (nb <= SCAP) {
        for (int i = base + t; i < end; i += 1024) {
            unsigned p = pairs[i];
            int rl = p & (BROWS - 1);
            int pos = roff[rl] + atomicAdd(&lcur[rl], 1);
            srt[pos] = (int)(p >> 10);
        }
        __syncthreads();
        for (int j = t; j < nb; j += 1024)
            col[base + j] = srt[j];
    } else {
        for (int i = base + t; i < end; i += 1024) {
            unsigned p = pairs[i];
            int rl = p & (BROWS - 1);
            int pos = base + roff[rl] + atomicAdd(&lcur[rl], 1);
            col[pos] = (int)(p >> 10);
        }
    }
}

// ---- global scan ------------------------------------------------------

__global__ void scan1_kernel(const int* __restrict__ cnt, int* __restrict__ rp,
                             int* __restrict__ part, int n) {
    __shared__ int sh[1024];
    int t = threadIdx.x;
    int i = blockIdx.x * 1024 + t;
    int v = (i < n) ? cnt[i] : 0;
    sh[t] = v;
    __syncthreads();
    for (int off = 1; off < 1024; off <<= 1) {
        int u = (t >= off) ? sh[t - off] : 0;
        __syncthreads();
        sh[t] += u;
        __syncthreads();
    }
    if (i < n) rp[i] = sh[t] - v;
    if (t == 1023) part[blockIdx.x] = sh[1023];
}

__global__ void scan2_kernel(int* part, int m) {
    __shared__ int sh[256];
    __shared__ int carry;
    int t = threadIdx.x;
    if (t == 0) carry = 0;
    __syncthreads();
    for (int base = 0; base < m; base += 256) {
        int i = base + t;
        int v = (i < m) ? part[i] : 0;
        sh[t] = v;
        __syncthreads();
        for (int off = 1; off < 256; off <<= 1) {
            int u = (t >= off) ? sh[t - off] : 0;
            __syncthreads();
            sh[t] += u;
            __syncthreads();
        }
        if (i < m) part[i] = sh[t] - v + carry;
        __syncthreads();
        if (t == 255) carry += sh[255];
        __syncthreads();
    }
}

__global__ void scan3_kernel(int* __restrict__ rp, const int* __restrict__ part, int n) {
    int i = blockIdx.x * blockDim.x + threadIdx.x;
    if (i < n) rp[i] += part[i >> 10];
}

// ---- bf16 helpers ------------------------------------------------------

__device__ inline unsigned bf16rne(float f) {
    unsigned u = __float_as_uint(f);
    return (u + 0x7fffu + ((u >> 16) & 1u)) >> 16;
}
__device__ inline float bfl(unsigned u) { return __uint_as_float(u << 16); }
__device__ inline float bfh(unsigned u) { return __uint_as_float(u & 0xffff0000u); }

// ---- xsb prep + out init ----------------------------------------------

__global__ void xsb_kernel(const float* __restrict__ x, const float* __restrict__ nrm,
                           uint2* __restrict__ xsb, int n) {
    int r = blockIdx.x * blockDim.x + threadIdx.x;
    if (r >= n) return;
    float nm = nrm[r];
    float4 v = *(const float4*)(x + (size_t)r * 4);
    xsb[r] = make_uint2(bf16rne(v.x * nm) | (bf16rne(v.y * nm) << 16),
                        bf16rne(v.z * nm) | (bf16rne(v.w * nm) << 16));
}

__global__ void init_out_kernel(float* out, const float* __restrict__ lin_b) {
    int i = threadIdx.x;
    if (i < GG) out[i] = lin_b[0];
}

// ---- conv schedule (26 steps = 2 passes x 13), R13-R17-verified --------

struct Step {
    int buf, ns, bsel, gbase, rlo, wh;
    int e0on, e0n, e0h, e0w, e0r;
    int e1on, e1n, e1h, e1w, e1r;
};

__device__ __constant__ Step SCHED[26] = {
    // pass 0
    {SA_O, NS_IN(0), 0, 0, 0, 0,        1, NS_F(0), F0_O, 1, 0,              1, NS_B(0), B0_O, 2, 1},
    {F0_O, NS_F(0), 1, 0, NLK, 0,       1, NS_IN(1), SB_O, 0, 0,             0,0,0,0,0},
    {SB_O, NS_IN(1), 0, NLK, 0, 0,      1, NS_F(1), F1_O, 1, 0,              1, NS_B(1), B1_O, 2, 1},
    {F1_O, NS_F(1), 1, NLK, NLK, 0,     1, NS_IN(2), SC_O, 0, 0,             0,0,0,0,0},
    {SC_O, NS_IN(2), 0, 2*NLK, 0, 0,    1, NS_F(2), F2_O, 1, 0,              1, NS_B(2), B2_O, 2, 1},
    {F2_O, NS_F(2), 1, 2*NLK, NLK, 0,   1, NS_IN(3), SA_O, 0, 0,             0,0,0,0,0},
    {SA_O, NS_IN(3), 0, 3*NLK, 0, 0,    1, NS_B(2)+NLK, B2_O+SLOT_U, 2, 1,   1, NS_F(2)+NLK, F2_O+SLOT_U, 1, 1},
    {B2_O, NS_B(2), 2, 2*NLK, 0, 0,     1, NS_IN(2), SC_O, 0, 0,             0,0,0,0,0},
    {SC_O, NS_IN(2), 0, 2*NLK, 0, 0,    1, NS_B(1)+NLK, B1_O+SLOT_U, 2, 0,   1, NS_F(1)+NLK, F1_O+SLOT_U, 1, 1},
    {B1_O, NS_B(1), 2, NLK, 0, 0,       1, NS_IN(1), SB_O, 0, 0,             0,0,0,0,0},
    {SB_O, NS_IN(1), 0, NLK, 0, 0,      1, NS_B(0)+NLK, B0_O+SLOT_U, 2, 0,   1, NS_F(0)+NLK, F0_O+SLOT_U, 1, 1},
    {B0_O, NS_B(0), 2, 0, 0, 0,         1, NS_IN(0), SD_O, 0, 0,             0,0,0,0,0},
    {SD_O, NS_IN(0), 0, 0, 0, 0,        1, NS_IN(0), SA_O, 0, 1,             0,0,0,0,0},
    // pass 1
    {SA_O, NS_IN(0), 0, 0, 0, 0,        1, NS_F(0), F0_O, 1, 0,              1, NS_B(0), B0_O, 2, 1},
    {F0_O, NS_F(0), 1, 0, NLK, 0,       1, NS_IN(1), SB_O, 0, 0,             0,0,0,0,0},
    {SB_O, NS_IN(1), 0, NLK, 0, 0,      1, NS_F(1), F1_O, 1, 0,              1, NS_B(1), B1_O, 2, 1},
    {F1_O, NS_F(1), 1, NLK, NLK, 0,     1, NS_IN(2), SC_O, 0, 0,             0,0,0,0,0},
    {SC_O, NS_IN(2), 0, 2*NLK, 0, 0,    1, NS_F(2), F2_O, 1, 0,              1, NS_B(2), B2_O, 2, 1},
    {F2_O, NS_F(2), 1, 2*NLK, NLK, 0,   1, NS_IN(3), SA_O, 0, 0,             0,0,0,0,0},
    {SA_O, NS_IN(3), 0, 3*NLK, 0, 1,    1, NS_B(2)+NLK, B2_O+SLOT_U, 2, 1,   0,0,0,0,0},
    {B2_O, NS_B(2), 2, 2*NLK, 0, 0,     1, NS_IN(2), SC_O, 0, 0,             0,0,0,0,0},
    {SC_O, NS_IN(2), 0, 2*NLK, 0, 1,    1, NS_B(1)+NLK, B1_O+SLOT_U, 2, 0,   0,0,0,0,0},
    {B1_O, NS_B(1), 2, NLK, 0, 0,       1, NS_IN(1), SB_O, 0, 0,             0,0,0,0,0},
    {SB_O, NS_IN(1), 0, NLK, 0, 1,      1, NS_B(0)+NLK, B0_O+SLOT_U, 2, 0,   0,0,0,0,0},
    {B0_O, NS_B(0), 2, 0, 0, 0,         1, NS_IN(0), SD_O, 0, 0,             0,0,0,0,0},
    {SD_O, NS_IN(0), 0, 0, 0, 1,        0,0,0,0,0,                           0,0,0,0,0},
};

// ---- cooperative mega-kernel: up conv + 26 convs + pool ----------------
// 512 blocks x 512 thr = 2 blocks/CU: launch-boundary-free AND full TLP.

__global__ void __launch_bounds__(MTHR, 4)
mega_kernel(const int* __restrict__ rp, const int* __restrict__ col,
            unsigned* __restrict__ hsbp, const float* __restrict__ norms,
            float* __restrict__ h, const float* __restrict__ stat,
            const uint2* __restrict__ xsb,
            const float* __restrict__ W_in, const float* __restrict__ b_in,
            const float* __restrict__ W_f, const float* __restrict__ b_f,
            const float* __restrict__ W_b, const float* __restrict__ b_b,
            const float* __restrict__ W_up, const float* __restrict__ b_up,
            const int* __restrict__ gids, const float* __restrict__ lin_W,
            float* __restrict__ out) {
    cg::grid_group grid = cg::this_grid();
    __shared__ float WA[1280];
    __shared__ float WB[1280];
    __shared__ float Wu[128];
    __shared__ float bu[32];
    __shared__ float rowbuf[64][41];
    __shared__ float part[GG];
    int t = threadIdx.x;
    int j = t & 7;
    int lrow = t >> 3;
    int hw = j * 2;
    int q = j * 4;

    // ======== phase U: up conv (pull4 + 4x32 mm + per-layer emission) ========
    for (int i = t; i < 128; i += MTHR) Wu[i] = W_up[i];
    if (t < 32) bu[t] = b_up[t];
    for (int i = t; i < 1280; i += MTHR) { WA[i] = W_in[i]; WB[i] = W_f[i]; }
    __syncthreads();
    for (int it = 0; it < 8; it++) {
        int tid = it * (MBLK * MTHR) + blockIdx.x * MTHR + t;
        int g = tid >> 3;
        int ea = rp[g], eb = rp[g + 1];
        float a0 = 0.f, a1 = 0.f, a2 = 0.f, a3 = 0.f;
        int e = ea + j;
        for (; e + 8 < eb; e += 16) {
            uint2 v0 = xsb[col[e]];
            uint2 v1 = xsb[col[e + 8]];
            a0 += bfl(v0.x) + bfl(v1.x); a1 += bfh(v0.x) + bfh(v1.x);
            a2 += bfl(v0.y) + bfl(v1.y); a3 += bfh(v0.y) + bfh(v1.y);
        }
        if (e < eb) {
            uint2 v = xsb[col[e]];
            a0 += bfl(v.x); a1 += bfh(v.x); a2 += bfl(v.y); a3 += bfh(v.y);
        }
#pragma unroll
        for (int m = 1; m < 8; m <<= 1) {
            a0 += __shfl_xor(a0, m);
            a1 += __shfl_xor(a1, m);
            a2 += __shfl_xor(a2, m);
            a3 += __shfl_xor(a3, m);
        }
        uint2 sv = xsb[g];
        a0 += bfl(sv.x); a1 += bfh(sv.x); a2 += bfl(sv.y); a3 += bfh(sv.y);
        float nm = norms[g];
#pragma unroll
        for (int d = 0; d < 4; d++) {
            float s = a0 * Wu[q + d] + a1 * Wu[32 + q + d] + a2 * Wu[64 + q + d] + a3 * Wu[96 + q + d];
            rowbuf[lrow][q + d] = fmaf(s, nm, bu[q + d]);
        }
        rowbuf[lrow][32 + j] = stat[(size_t)g * 8 + j];
        __syncthreads();
        int l = g >> 16;
        const float* W = (l == 0) ? WA : WB;
        int noff = (l == 0) ? NS_IN(0) : (l == 1) ? NS_F(0) : (l == 2) ? (NS_F(1) - NLK) : (NS_F(2) - 2 * NLK);
        int hoff = (l == 0) ? SA_O : (l == 1) ? F0_O : (l == 2) ? (F1_O - SLOT_U) : (F2_O - 2 * SLOT_U);
        float nmc = norms[noff + g];
        float r0 = 0, r1 = 0, r2 = 0, r3 = 0;
#pragma unroll
        for (int k = 0; k < 40; k++) {
            float v = rowbuf[lrow][k];
            const float* Wp = &W[k * 32 + q];
            r0 = fmaf(v, Wp[0], r0); r1 = fmaf(v, Wp[1], r1);
            r2 = fmaf(v, Wp[2], r2); r3 = fmaf(v, Wp[3], r3);
        }
        unsigned u0 = bf16rne(r0 * nmc) | (bf16rne(r1 * nmc) << 16);
        unsigned u1 = bf16rne(r2 * nmc) | (bf16rne(r3 * nmc) << 16);
        *(uint2*)(hsbp + (size_t)hoff + (size_t)g * 16 + hw) = make_uint2(u0, u1);
        __syncthreads();
    }
    __threadfence();
    grid.sync();

    // ======== 26 conv phases ========
    for (int s = 0; s < 26; s++) {
        Step S = SCHED[s];
        const float* bias = (S.bsel == 0) ? b_in : (S.bsel == 1) ? b_f : b_b;
        if (S.e0on) {
            const float* Wt = (S.e0w == 0) ? W_in : (S.e0w == 1) ? W_f : W_b;
            for (int i = t; i < 1280; i += MTHR) WA[i] = Wt[i];
        }
        if (S.e1on) {
            const float* Wt = (S.e1w == 0) ? W_in : (S.e1w == 1) ? W_f : W_b;
            for (int i = t; i < 1280; i += MTHR) WB[i] = Wt[i];
        }
        __syncthreads();
        const unsigned* hin = hsbp + S.buf;
        for (int it = 0; it < 2; it++) {
            int tid = it * (MBLK * MTHR) + blockIdx.x * MTHR + t;
            int rr = tid >> 3;
            int r = S.rlo + rr;
            int ea = rp[S.ns + r], eb = rp[S.ns + r + 1];
            uint2 sv = *(const uint2*)(hin + (size_t)r * 16 + hw);
            float a0 = bfl(sv.x), a1 = bfh(sv.x), a2 = bfl(sv.y), a3 = bfh(sv.y);
            int e = ea;
            for (; e + 2 <= eb; e += 2) {
                int s0 = col[e];
                int s1 = col[e + 1];
                uint2 v0 = *(const uint2*)(hin + (size_t)s0 * 16 + hw);
                uint2 v1 = *(const uint2*)(hin + (size_t)s1 * 16 + hw);
                a0 += bfl(v0.x) + bfl(v1.x); a1 += bfh(v0.x) + bfh(v1.x);
                a2 += bfl(v0.y) + bfl(v1.y); a3 += bfh(v0.y) + bfh(v1.y);
            }
            if (e < eb) {
                int s0 = col[e];
                uint2 v = *(const uint2*)(hin + (size_t)s0 * 16 + hw);
                a0 += bfl(v.x); a1 += bfh(v.x); a2 += bfl(v.y); a3 += bfh(v.y);
            }
            float nm = norms[S.ns + r];
            float4 bv = *(const float4*)(bias + q);
            float o0 = fmaf(a0, nm, bv.x), o1 = fmaf(a1, nm, bv.y);
            float o2 = fmaf(a2, nm, bv.z), o3 = fmaf(a3, nm, bv.w);
            if (S.wh)
                *(float4*)(h + (size_t)(S.gbase + S.rlo + rr) * DYNF + q) = make_float4(o0, o1, o2, o3);
            rowbuf[lrow][q] = o0; rowbuf[lrow][q + 1] = o1;
            rowbuf[lrow][q + 2] = o2; rowbuf[lrow][q + 3] = o3;
            rowbuf[lrow][32 + j] = stat[(size_t)(S.gbase + S.rlo + rr) * 8 + j];
            __syncthreads();
            if (S.e0on) {
                float nmc = norms[S.e0n + rr];
                float r0 = 0, r1 = 0, r2 = 0, r3 = 0;
#pragma unroll
                for (int k = 0; k < 40; k++) {
                    float v = rowbuf[lrow][k];
                    if (k < 32 && S.e0r) v = fmaxf(v, 0.f);
                    const float* Wp = &WA[k * 32 + q];
                    r0 = fmaf(v, Wp[0], r0); r1 = fmaf(v, Wp[1], r1);
                    r2 = fmaf(v, Wp[2], r2); r3 = fmaf(v, Wp[3], r3);
                }
                unsigned u0 = bf16rne(r0 * nmc) | (bf16rne(r1 * nmc) << 16);
                unsigned u1 = bf16rne(r2 * nmc) | (bf16rne(r3 * nmc) << 16);
                *(uint2*)(hsbp + (size_t)S.e0h + (size_t)rr * 16 + hw) = make_uint2(u0, u1);
            }
            if (S.e1on) {
                float nmc = norms[S.e1n + rr];
                float r0 = 0, r1 = 0, r2 = 0, r3 = 0;
#pragma unroll
                for (int k = 0; k < 40; k++) {
                    float v = rowbuf[lrow][k];
                    if (k < 32 && S.e1r) v = fmaxf(v, 0.f);
                    const float* Wp = &WB[k * 32 + q];
                    r0 = fmaf(v, Wp[0], r0); r1 = fmaf(v, Wp[1], r1);
                    r2 = fmaf(v, Wp[2], r2); r3 = fmaf(v, Wp[3], r3);
                }
                unsigned u0 = bf16rne(r0 * nmc) | (bf16rne(r1 * nmc) << 16);
                unsigned u1 = bf16rne(r2 * nmc) | (bf16rne(r3 * nmc) << 16);
                *(uint2*)(hsbp + (size_t)S.e1h + (size_t)rr * 16 + hw) = make_uint2(u0, u1);
            }
            __syncthreads();
        }
        __threadfence();
        grid.sync();
    }

    // ======== pool phase (final relu fused) ========
    if (t < GG) part[t] = 0.f;
    __syncthreads();
    int r = blockIdx.x * MTHR + t;                  // exactly NN threads
    float dotv = 0.f;
    const float4* hp = (const float4*)(h + (size_t)r * DYNF);
#pragma unroll
    for (int qq = 0; qq < 8; qq++) {
        float4 v = hp[qq];
        dotv += fmaxf(v.x, 0.f) * lin_W[qq * 4 + 0] + fmaxf(v.y, 0.f) * lin_W[qq * 4 + 1] +
                fmaxf(v.z, 0.f) * lin_W[qq * 4 + 2] + fmaxf(v.w, 0.f) * lin_W[qq * 4 + 3];
    }
    atomicAdd(&part[gids[r]], dotv);
    __syncthreads();
    if (t < GG) unsafeAtomicAdd(&out[t], part[t]);
}

// ---- R17 fallback kernels (pull + pack-emission path) ------------------

struct EmitArg {
    const float* nrm;
    unsigned*    hsb;
    const float* W;
    int relu;
    int on;
};

__global__ void pull_emit_kernel(const int* __restrict__ rp, const int* __restrict__ col,
                                 const unsigned* __restrict__ hsb_in, const float* __restrict__ nrm,
                                 const float* __restrict__ b, float* __restrict__ out,
                                 const float* __restrict__ stat_p, int row_lo, int write_h,
                                 EmitArg em0, EmitArg em1) {
    __shared__ float W0[1280];
    __shared__ float W1[1280];
    __shared__ float rowbuf[32][41];
    int t = threadIdx.x;
    if (em0.on) for (int i = t; i < 1280; i += 256) W0[i] = em0.W[i];
    if (em1.on) for (int i = t; i < 1280; i += 256) W1[i] = em1.W[i];
    int tid = blockIdx.x * 256 + t;
    int rr = tid >> 3;
    int r = row_lo + rr;
    int j = tid & 7;
    int hw = j * 2;
    int ea = rp[r], eb = rp[r + 1];
    uint2 sv = *(const uint2*)(hsb_in + (size_t)r * 16 + hw);
    float a0 = bfl(sv.x), a1 = bfh(sv.x), a2 = bfl(sv.y), a3 = bfh(sv.y);
    int e = ea;
    for (; e + 2 <= eb; e += 2) {
        int s0 = col[e];
        int s1 = col[e + 1];
        uint2 v0 = *(const uint2*)(hsb_in + (size_t)s0 * 16 + hw);
        uint2 v1 = *(const uint2*)(hsb_in + (size_t)s1 * 16 + hw);
        a0 += bfl(v0.x) + bfl(v1.x); a1 += bfh(v0.x) + bfh(v1.x);
        a2 += bfl(v0.y) + bfl(v1.y); a3 += bfh(v0.y) + bfh(v1.y);
    }
    if (e < eb) {
        int s = col[e];
        uint2 v = *(const uint2*)(hsb_in + (size_t)s * 16 + hw);
        a0 += bfl(v.x); a1 += bfh(v.x); a2 += bfl(v.y); a3 += bfh(v.y);
    }
    float nm = nrm[r];
    int q = j * 4;
    float4 bv = *(const float4*)(b + q);
    float o0 = fmaf(a0, nm, bv.x), o1 = fmaf(a1, nm, bv.y);
    float o2 = fmaf(a2, nm, bv.z), o3 = fmaf(a3, nm, bv.w);
    if (write_h)
        *(float4*)(out + (size_t)r * DYNF + q) = make_float4(o0, o1, o2, o3);
    if (!em0.on && !em1.on) return;
    int lrow = t >> 3;
    rowbuf[lrow][q] = o0; rowbuf[lrow][q + 1] = o1;
    rowbuf[lrow][q + 2] = o2; rowbuf[lrow][q + 3] = o3;
    rowbuf[lrow][32 + j] = stat_p[(size_t)rr * 8 + j];
    __syncthreads();
    if (em0.on) {
        float nmc = em0.nrm[rr];
        float r0 = 0, r1 = 0, r2 = 0, r3 = 0;
#pragma unroll
        for (int k = 0; k < 40; k++) {
            float v = rowbuf[lrow][k];
            if (k < 32 && em0.relu) v = fmaxf(v, 0.f);
            const float* Wp = &W0[k * 32 + q];
            r0 = fmaf(v, Wp[0], r0); r1 = fmaf(v, Wp[1], r1);
            r2 = fmaf(v, Wp[2], r2); r3 = fmaf(v, Wp[3], r3);
        }
        unsigned u0 = bf16rne(r0 * nmc) | (bf16rne(r1 * nmc) << 16);
        unsigned u1 = bf16rne(r2 * nmc) | (bf16rne(r3 * nmc) << 16);
        *(uint2*)(em0.hsb + (size_t)rr * 16 + hw) = make_uint2(u0, u1);
    }
    if (em1.on) {
        float nmc = em1.nrm[rr];
        float r0 = 0, r1 = 0, r2 = 0, r3 = 0;
#pragma unroll
        for (int k = 0; k < 40; k++) {
            float v = rowbuf[lrow][k];
            if (k < 32 && em1.relu) v = fmaxf(v, 0.f);
            const float* Wp = &W1[k * 32 + q];
            r0 = fmaf(v, Wp[0], r0); r1 = fmaf(v, Wp[1], r1);
            r2 = fmaf(v, Wp[2], r2); r3 = fmaf(v, Wp[3], r3);
        }
        unsigned u0 = bf16rne(r0 * nmc) | (bf16rne(r1 * nmc) << 16);
        unsigned u1 = bf16rne(r2 * nmc) | (bf16rne(r3 * nmc) << 16);
        *(uint2*)(em1.hsb + (size_t)rr * 16 + hw) = make_uint2(u0, u1);
    }
}

struct UpEmit {
    const float* n0; const float* n1; const float* n2; const float* n3;
    unsigned* h0; unsigned* h1; unsigned* h2; unsigned* h3;
};

__global__ void pull4mm_emit_kernel(const int* __restrict__ rp0, const int* __restrict__ col,
                                    const uint2* __restrict__ xsb, const float* __restrict__ Wup,
                                    const float* __restrict__ nrm, const float* __restrict__ bup,
                                    const float* __restrict__ Win, const float* __restrict__ Wf,
                                    const float* __restrict__ stat, UpEmit ue) {
    __shared__ float Ws[128];
    __shared__ float bs[32];
    __shared__ float Wa[1280];
    __shared__ float Wb[1280];
    __shared__ float rowbuf[32][41];
    int t = threadIdx.x;
    for (int i = t; i < 128; i += 256) Ws[i] = Wup[i];
    if (t < 32) bs[t] = bup[t];
    for (int i = t; i < 1280; i += 256) { Wa[i] = Win[i]; Wb[i] = Wf[i]; }
    __syncthreads();
    int tid = blockIdx.x * 256 + t;
    int g = tid >> 3;
    int j = t & 7;
    int ea = rp0[g], eb = rp0[g + 1];
    float a0 = 0.f, a1 = 0.f, a2 = 0.f, a3 = 0.f;
    int e = ea + j;
    for (; e + 8 < eb; e += 16) {
        uint2 v0 = xsb[col[e]];
        uint2 v1 = xsb[col[e + 8]];
        a0 += bfl(v0.x) + bfl(v1.x); a1 += bfh(v0.x) + bfh(v1.x);
        a2 += bfl(v0.y) + bfl(v1.y); a3 += bfh(v0.y) + bfh(v1.y);
    }
    if (e < eb) {
        uint2 v = xsb[col[e]];
        a0 += bfl(v.x); a1 += bfh(v.x); a2 += bfl(v.y); a3 += bfh(v.y);
    }
#pragma unroll
    for (int m = 1; m < 8; m <<= 1) {
        a0 += __shfl_xor(a0, m);
        a1 += __shfl_xor(a1, m);
        a2 += __shfl_xor(a2, m);
        a3 += __shfl_xor(a3, m);
    }
    uint2 sv = xsb[g];
    a0 += bfl(sv.x); a1 += bfh(sv.x); a2 += bfl(sv.y); a3 += bfh(sv.y);
    float nm = nrm[g];
    int q = j * 4;
    int lrow = t >> 3;
#pragma unroll
    for (int d = 0; d < 4; d++) {
        float s = a0 * Ws[q + d] + a1 * Ws[32 + q + d] + a2 * Ws[64 + q + d] + a3 * Ws[96 + q + d];
        rowbuf[lrow][q + d] = fmaf(s, nm, bs[q + d]);
    }
    rowbuf[lrow][32 + j] = stat[(size_t)g * 8 + j];
    __syncthreads();
    int l = g >> 16;
    const float* W = (l == 0) ? Wa : Wb;
    const float* nc = (l == 0) ? ue.n0 : (l == 1) ? ue.n1 : (l == 2) ? ue.n2 : ue.n3;
    unsigned* hb = (l == 0) ? ue.h0 : (l == 1) ? ue.h1 : (l == 2) ? ue.h2 : ue.h3;
    float nmc = nc[g];
    float r0 = 0, r1 = 0, r2 = 0, r3 = 0;
#pragma unroll
    for (int k = 0; k < 40; k++) {
        float v = rowbuf[lrow][k];
        const float* Wp = &W[k * 32 + q];
        r0 = fmaf(v, Wp[0], r0); r1 = fmaf(v, Wp[1], r1);
        r2 = fmaf(v, Wp[2], r2); r3 = fmaf(v, Wp[3], r3);
    }
    unsigned u0 = bf16rne(r0 * nmc) | (bf16rne(r1 * nmc) << 16);
    unsigned u1 = bf16rne(r2 * nmc) | (bf16rne(r3 * nmc) << 16);
    *(uint2*)(hb + (size_t)g * 16 + j * 2) = make_uint2(u0, u1);
}

__global__ void pool_kernel(const float* __restrict__ h, const int* __restrict__ gids,
                            const float* __restrict__ linW, float* out) {
    __shared__ float part[GG];
    int t = threadIdx.x;
    if (t < GG) part[t] = 0.f;
    __syncthreads();
    int r = blockIdx.x * blockDim.x + t;
    float dotv = 0.f;
    const float4* hp = (const float4*)(h + (size_t)r * DYNF);
#pragma unroll
    for (int q = 0; q < 8; q++) {
        float4 v = hp[q];
        dotv += fmaxf(v.x, 0.f) * linW[q * 4 + 0] + fmaxf(v.y, 0.f) * linW[q * 4 + 1] +
                fmaxf(v.z, 0.f) * linW[q * 4 + 2] + fmaxf(v.w, 0.f) * linW[q * 4 + 3];
    }
    atomicAdd(&part[gids[r]], dotv);
    __syncthreads();
    if (t < GG) unsafeAtomicAdd(&out[t], part[t]);
}

// ------------------------------------------------------------------------

extern "C" void kernel_launch(void* const* d_in, const int* in_sizes, int n_in,
                              void* d_out, int out_size, void* d_ws, size_t ws_size,
                              hipStream_t stream) {
    const float* x     = (const float*)d_in[0];
    const float* stat  = (const float*)d_in[1];
    const int*   e_up  = (const int*)d_in[2];
    const int*   e_in  = (const int*)d_in[3];
    const int*   e_f   = (const int*)d_in[4];
    const int*   e_b   = (const int*)d_in[5];
    const int*   gids  = (const int*)d_in[6];
    const float* W_up  = (const float*)d_in[7];
    const float* b_up  = (const float*)d_in[8];
    const float* W_in  = (const float*)d_in[9];
    const float* b_in  = (const float*)d_in[10];
    const float* W_f   = (const float*)d_in[11];
    const float* b_f   = (const float*)d_in[12];
    const float* W_b   = (const float*)d_in[13];
    const float* b_b   = (const float*)d_in[14];
    const float* lin_W = (const float*)d_in[15];
    const float* lin_b = (const float*)d_in[16];
    float* out = (float*)d_out;

    // ---- workspace carve (~172 MB peak) ----
    float*    norms = (float*)d_ws;                              // NS_TOT
    int*      rp    = (int*)(norms + NS_TOT);                    // NS_TOT+1
    int*      col   = rp + NS_TOT + 1;                           // CO_TOT
    unsigned* H0    = (unsigned*)(col + CO_TOT);                 // conv region base
    float*    h     = (float*)H0;                                // NN*32 f32
    unsigned* hsbp  = H0 + (size_t)NN * DYNF;                    // pack pool: 16*NLK rows *16 u32
    uint2*    xsb   = (uint2*)(hsbp + (size_t)16 * NLK * 16);    // NN uint2 (dedicated)
    unsigned* pairs = H0;                                        // build alias (CO_TOT u32)
    int*      hmat  = (int*)(H0 + CO_TOT);                       // HM
    int*      smat  = hmat + HM;                                 // HM
    int*      part  = smat + HM;                                 // >= 560

    unsigned* SA  = hsbp + (size_t)0  * SLOT_U;
    unsigned* SB  = hsbp + (size_t)1  * SLOT_U;
    unsigned* SC  = hsbp + (size_t)2  * SLOT_U;
    unsigned* SD  = hsbp + (size_t)3  * SLOT_U;
    unsigned* F0b = hsbp + (size_t)4  * SLOT_U;
    unsigned* F1b = hsbp + (size_t)6  * SLOT_U;
    unsigned* F2b = hsbp + (size_t)8  * SLOT_U;
    unsigned* B0b = hsbp + (size_t)10 * SLOT_U;
    unsigned* B1b = hsbp + (size_t)12 * SLOT_U;
    unsigned* B2b = hsbp + (size_t)14 * SLOT_U;

    // ---- build: zero-global-atomic radix partition + LDS-staged passes ----
    hist_part_kernel<<<NB, 1024, 0, stream>>>(e_up, e_in, e_f, e_b, hmat);
    scan1_kernel<<<HM / 1024, 1024, 0, stream>>>(hmat, smat, part, HM);
    scan2_kernel<<<1, 256, 0, stream>>>(part, HM / 1024);
    scan3_kernel<<<cdiv(HM, 256), 256, 0, stream>>>(smat, part, HM);
    scatter_part_kernel<<<NB, 1024, 0, stream>>>(e_up, e_in, e_f, e_b, hmat, smat, pairs);
    group_kernel<<<NBUCK, 1024, 0, stream>>>(pairs, smat, col, rp, norms);

    // ---- prep: xsb + out init ----
    xsb_kernel<<<cdiv(NN, 256), 256, 0, stream>>>(x, norms + NS_UP, xsb, NN);
    init_out_kernel<<<1, 64, 0, stream>>>(out, lin_b);

    // ---- cooperative-capability check (stream-free, deterministic) ----
    int coopAttr = 0, dev = 0, maxB = 0, numCU = 0;
    hipGetDevice(&dev);
    hipDeviceGetAttribute(&coopAttr, hipDeviceAttributeCooperativeLaunch, dev);
    hipDeviceGetAttribute(&numCU, hipDeviceAttributeMultiprocessorCount, dev);
    hipOccupancyMaxActiveBlocksPerMultiprocessor(&maxB, mega_kernel, MTHR, 0);
    bool use_coop = (coopAttr != 0) && ((long)maxB * numCU >= MBLK);

    if (use_coop) {
        const int* a_rp = rp; const int* a_col = col;
        unsigned* a_hsbp = hsbp; const float* a_norms = norms;
        float* a_h = h; const float* a_stat = stat;
        const uint2* a_xsb = xsb;
        const float* a_Win = W_in; const float* a_bin = b_in;
        const float* a_Wf = W_f; const float* a_bf = b_f;
        const float* a_Wb = W_b; const float* a_bb = b_b;
        const float* a_Wup = W_up; const float* a_bup = b_up;
        const int* a_gids = gids; const float* a_linW = lin_W;
        float* a_out = out;
        void* args[] = { &a_rp, &a_col, &a_hsbp, &a_norms, &a_h, &a_stat, &a_xsb,
                         &a_Win, &a_bin, &a_Wf, &a_bf, &a_Wb, &a_bb, &a_Wup, &a_bup,
                         &a_gids, &a_linW, &a_out };
        hipLaunchCooperativeKernel((void*)mega_kernel, dim3(MBLK), dim3(MTHR),
                                   args, 0, stream);
        return;
    }

    // ---- fallback: R17 multi-kernel path ----
    UpEmit ue;
    ue.n0 = norms + NS_IN(0);
    ue.n1 = norms + NS_F(0);
    ue.n2 = norms + NS_F(1) - NLK;
    ue.n3 = norms + NS_F(2) - 2 * NLK;
    ue.h0 = SA;
    ue.h1 = F0b;
    ue.h2 = F1b - (size_t)SLOT_U;
    ue.h3 = F2b - (size_t)2 * SLOT_U;
    pull4mm_emit_kernel<<<(NN * 8) / 256, 256, 0, stream>>>(rp + NS_UP, col, xsb, W_up,
                                                            norms + NS_UP, b_up, W_in, W_f, stat, ue);

    auto EM = [&](const float* n, unsigned* hb, const float* W, int rl) {
        EmitArg e; e.nrm = n; e.hsb = hb; e.W = W; e.relu = rl; e.on = 1; return e;
    };
    EmitArg OFF; OFF.nrm = nullptr; OFF.hsb = nullptr; OFF.W = nullptr; OFF.relu = 0; OFF.on = 0;

    auto P = [&](unsigned* buf, int ns, const float* bias, int gbase, int row_lo,
                 int wh, EmitArg a, EmitArg c) {
        pull_emit_kernel<<<(NLK * 8) / 256, 256, 0, stream>>>(
            rp + ns, col, buf, norms + ns, bias, h + (size_t)gbase * DYNF,
            stat + (size_t)(gbase + row_lo) * STATF, row_lo, wh, a, c);
    };

    for (int p = 0; p < 2; p++) {
        P(SA, NS_IN(0), b_in, 0, 0, 0,
          EM(norms + NS_F(0), F0b, W_f, 0), EM(norms + NS_B(0), B0b, W_b, 1));
        P(F0b, NS_F(0), b_f, 0, NLK, 0,
          EM(norms + NS_IN(1), SB, W_in, 0), OFF);
        P(SB, NS_IN(1), b_in, NLK, 0, 0,
          EM(norms + NS_F(1), F1b, W_f, 0), EM(norms + NS_B(1), B1b, W_b, 1));
        P(F1b, NS_F(1), b_f, NLK, NLK, 0,
          EM(norms + NS_IN(2), SC, W_in, 0), OFF);
        P(SC, NS_IN(2), b_in, 2 * NLK, 0, 0,
          EM(norms + NS_F(2), F2b, W_f, 0), EM(norms + NS_B(2), B2b, W_b, 1));
        P(F2b, NS_F(2), b_f, 2 * NLK, NLK, 0,
          EM(norms + NS_IN(3), SA, W_in, 0), OFF);
        P(SA, NS_IN(3), b_in, 3 * NLK, 0, (p == 1),
          EM(norms + NS_B(2) + NLK, B2b + (size_t)SLOT_U, W_b, 1),
          p == 0 ? EM(norms + NS_F(2) + NLK, F2b + (size_t)SLOT_U, W_f, 1) : OFF);
        P(B2b, NS_B(2), b_b, 2 * NLK, 0, 0,
          EM(norms + NS_IN(2), SC, W_in, 0), OFF);
        P(SC, NS_IN(2), b_in, 2 * NLK, 0, (p == 1),
          EM(norms + NS_B(1) + NLK, B1b + (size_t)SLOT_U, W_b, 0),
          p == 0 ? EM(norms + NS_F(1) + NLK, F1b + (size_t)SLOT_U, W_f, 1) : OFF);
        P(B1b, NS_B(1), b_b, NLK, 0, 0,
          EM(norms + NS_IN(1), SB, W_in, 0), OFF);
        P(SB, NS_IN(1), b_in, NLK, 0, (p == 1),
          EM(norms + NS_B(0) + NLK, B0b + (size_t)SLOT_U, W_b, 0),
          p == 0 ? EM(norms + NS_F(0) + NLK, F0b + (size_t)SLOT_U, W_f, 1) : OFF);
        P(B0b, NS_B(0), b_b, 0, 0, 0,
          EM(norms + NS_IN(0), SD, W_in, 0), OFF);
        P(SD, NS_IN(0), b_in, 0, 0, (p == 1),
          p == 0 ? EM(norms + NS_IN(0), SA, W_in, 1) : OFF, OFF);
    }

    pool_kernel<<<NN / 256, 256, 0, stream>>>(h, gids, lin_W, out);
}

// Round 21
// 757.167 us; speedup vs baseline: 1.0694x; 1.0662x over previous
//
#include <hip/hip_runtime.h>

#define NLK 65536
#define NN (NLK * 4)        // 262144 nodes
#define DYNF 32
#define STATF 8
#define GG 64
#define EUP 4194304
#define EIN 1048576
#define EFB 1048576

// unified row space: [up: NN][inner: 4*NLK][fwd: 3*2NLK][bwd: 3*2NLK]
#define NS_UP    0
#define NS_IN(l) (NN + (l) * NLK)
#define NS_F(l)  (NN + 4 * NLK + (l) * 2 * NLK)
#define NS_B(l)  (NN + 10 * NLK + (l) * 2 * NLK)
#define NS_TOT   (NN + 16 * NLK)                    // 1,310,720
#define CO_TOT   (EUP + 4 * EIN + 6 * EFB)          // 14,680,064

#define CHUNK 32768                                 // edges per partition block
#define NB    (CO_TOT / CHUNK)                      // 448 partition blocks
#define BROWS 1024                                  // rows per bucket
#define NBUCK (NS_TOT / BROWS)                      // 1280 buckets
#define HM    (NBUCK * NB)                          // 573,440
#define SCAP  20480                                 // group LDS sort capacity

#define SLOT_U (NLK * 16)

static inline int cdiv(long a, int b) { return (int)((a + b - 1) / b); }

// ---- which list does partition block b cover? --------------------------
__device__ inline void cdecode(int b, const int* e_up, const int* e_in,
                               const int* e_f, const int* e_b,
                               const int*& srcp, const int*& dstp, int& ns, int& e0) {
    if (b < EUP / CHUNK) { srcp = e_up; dstp = e_up + EUP; ns = NS_UP; e0 = b * CHUNK; return; }
    int t = b - EUP / CHUNK;
    int list = t >> 5;                               // 32 blocks per small list
    e0 = (t & 31) * CHUNK;
    if (list < 4) {
        srcp = e_in + (size_t)(2 * list) * EIN; dstp = srcp + EIN; ns = NS_IN(list);
    } else if (list < 7) {
        int l = list - 4;
        srcp = e_f + (size_t)(2 * l) * EFB; dstp = srcp + EFB; ns = NS_F(l);
    } else {
        int l = list - 7;
        srcp = e_b + (size_t)(2 * l) * EFB; dstp = srcp + EFB; ns = NS_B(l);
    }
}

// ---- pass 1: per-block LDS bucket histogram (1024 thr, int4 loads) -----
__global__ void hist_part_kernel(const int* __restrict__ e_up, const int* __restrict__ e_in,
                                 const int* __restrict__ e_f, const int* __restrict__ e_b,
                                 int* __restrict__ hmat) {
    __shared__ int lh[NBUCK];
    for (int k = threadIdx.x; k < NBUCK; k += 1024) lh[k] = 0;
    __syncthreads();
    const int *srcp, *dstp; int ns, e0;
    cdecode(blockIdx.x, e_up, e_in, e_f, e_b, srcp, dstp, ns, e0);
    for (int j = 0; j < CHUNK / 4096; j++) {        // 8 iters, 4 edges/thread/iter
        int4 d4 = *(const int4*)(dstp + e0 + (j * 1024 + threadIdx.x) * 4);
        atomicAdd(&lh[(ns + d4.x) >> 10], 1);
        atomicAdd(&lh[(ns + d4.y) >> 10], 1);
        atomicAdd(&lh[(ns + d4.z) >> 10], 1);
        atomicAdd(&lh[(ns + d4.w) >> 10], 1);
    }
    __syncthreads();
    for (int k = threadIdx.x; k < NBUCK; k += 1024)
        hmat[(size_t)k * NB + blockIdx.x] = lh[k];
}

// ---- pass 2: LDS-staged bucket sort -> coalesced slice flush (int4) ----
__global__ void scatter_part_kernel(const int* __restrict__ e_up, const int* __restrict__ e_in,
                                    const int* __restrict__ e_f, const int* __restrict__ e_b,
                                    const int* __restrict__ hmat, const int* __restrict__ smat,
                                    unsigned* __restrict__ pairs) {
    __shared__ unsigned srt[CHUNK];                 // 128 KB
    __shared__ int ls[NBUCK + 1];
    __shared__ int gbase[NBUCK];
    __shared__ int lcur[NBUCK];
    __shared__ int ssum[1024];
    int t = threadIdx.x;
    int b = blockIdx.x;
    const int *srcp, *dstp; int ns, e0;
    cdecode(b, e_up, e_in, e_f, e_b, srcp, dstp, ns, e0);
    int a0 = (2 * t < NBUCK) ? hmat[(size_t)(2 * t) * NB + b] : 0;
    int a1 = (2 * t + 1 < NBUCK) ? hmat[(size_t)(2 * t + 1) * NB + b] : 0;
    if (2 * t < NBUCK) gbase[2 * t] = smat[(size_t)(2 * t) * NB + b];
    if (2 * t + 1 < NBUCK) gbase[2 * t + 1] = smat[(size_t)(2 * t + 1) * NB + b];
    if (2 * t < NBUCK) lcur[2 * t] = 0;
    if (2 * t + 1 < NBUCK) lcur[2 * t + 1] = 0;
    int gsum = a0 + a1;
    ssum[t] = gsum;
    __syncthreads();
    for (int off = 1; off < 1024; off <<= 1) {
        int u = (t >= off) ? ssum[t - off] : 0;
        __syncthreads();
        ssum[t] += u;
        __syncthreads();
    }
    int run = ssum[t] - gsum;
    if (2 * t < NBUCK) ls[2 * t] = run;
    if (2 * t + 1 < NBUCK) ls[2 * t + 1] = run + a0;
    if (t == 0) ls[NBUCK] = CHUNK;                  // sentinel
    __syncthreads();
    for (int j = 0; j < CHUNK / 4096; j++) {        // int4: 4 edges/thread/iter
        int idx = e0 + (j * 1024 + t) * 4;
        int4 d4 = *(const int4*)(dstp + idx);
        int4 s4 = *(const int4*)(srcp + idx);
        int g, k, pos;
        g = ns + d4.x; k = g >> 10; pos = ls[k] + atomicAdd(&lcur[k], 1);
        srt[pos] = ((unsigned)s4.x << 10) | (unsigned)(g & (BROWS - 1));
        g = ns + d4.y; k = g >> 10; pos = ls[k] + atomicAdd(&lcur[k], 1);
        srt[pos] = ((unsigned)s4.y << 10) | (unsigned)(g & (BROWS - 1));
        g = ns + d4.z; k = g >> 10; pos = ls[k] + atomicAdd(&lcur[k], 1);
        srt[pos] = ((unsigned)s4.z << 10) | (unsigned)(g & (BROWS - 1));
        g = ns + d4.w; k = g >> 10; pos = ls[k] + atomicAdd(&lcur[k], 1);
        srt[pos] = ((unsigned)s4.w << 10) | (unsigned)(g & (BROWS - 1));
    }
    __syncthreads();
    int wave = t >> 6;
    int lane = t & 63;
    for (int k = wave; k < NBUCK; k += 16) {
        int lo = ls[k];
        int n = ls[k + 1] - lo;
        int dst = gbase[k];
        for (int i = lane; i < n; i += 64)
            pairs[dst + i] = srt[lo + i];
    }
}

// ---- pass 3: per-bucket group; LDS-staged sort -> sequential col (1024 thr)
__global__ void group_kernel(const unsigned* __restrict__ pairs, const int* __restrict__ smat,
                             int* __restrict__ col, int* __restrict__ rp,
                             float* __restrict__ norms) {
    __shared__ int srt[SCAP];
    __shared__ int lcnt[BROWS];
    __shared__ int roff[BROWS];
    __shared__ int lcur[BROWS];
    __shared__ int ssum[1024];
    int k = blockIdx.x;
    int t = threadIdx.x;
    int base = smat[(size_t)k * NB];
    int end  = (k + 1 < NBUCK) ? smat[(size_t)(k + 1) * NB] : CO_TOT;
    int nb = end - base;
    lcnt[t] = 0;
    lcur[t] = 0;
    __syncthreads();
    for (int i = base + t; i < end; i += 1024)
        atomicAdd(&lcnt[pairs[i] & (BROWS - 1)], 1);
    __syncthreads();
    int a0 = lcnt[t];
    ssum[t] = a0;
    __syncthreads();
    for (int off = 1; off < 1024; off <<= 1) {
        int u = (t >= off) ? ssum[t - off] : 0;
        __syncthreads();
        ssum[t] += u;
        __syncthreads();
    }
    int gex = ssum[t] - a0;
    roff[t] = gex;
    int row = k * BROWS + t;
    rp[row] = base + gex;
    norms[row] = rsqrtf((float)(a0 + 1));           // +1 self-loop
    if (k == 0 && t == 0) rp[NS_TOT] = CO_TOT;
    __syncthreads();
    if (nb <= SCAP) {
        for (int i = base + t; i < end; i += 1024) {
            unsigned p = pairs[i];
            int rl = p & (BROWS - 1);
            int pos = roff[rl] + atomicAdd(&lcur[rl], 1);
            srt[pos] = (int)(p >> 10);
        }
        __syncthreads();
        for (int j = t; j < nb; j += 1024)
            col[base + j] = srt[j];
    } else {
        for (int i = base + t; i < end; i += 1024) {
            unsigned p = pairs[i];
            int rl = p & (BROWS - 1);
            int pos = base + roff[rl] + atomicAdd(&lcur[rl], 1);
            col[pos] = (int)(p >> 10);
        }
    }
}

// ---- global scan ------------------------------------------------------

__global__ void scan1_kernel(const int* __restrict__ cnt, int* __restrict__ rp,
                             int* __restrict__ part, int n) {
    __shared__ int sh[1024];
    int t = threadIdx.x;
    int i = blockIdx.x * 1024 + t;
    int v = (i < n) ? cnt[i] : 0;
    sh[t] = v;
    __syncthreads();
    for (int off = 1; off < 1024; off <<= 1) {
        int u = (t >= off) ? sh[t - off] : 0;
        __syncthreads();
        sh[t] += u;
        __syncthreads();
    }
    if (i < n) rp[i] = sh[t] - v;
    if (t == 1023) part[blockIdx.x] = sh[1023];
}

__global__ void scan2_kernel(int* part, int m) {
    __shared__ int sh[256];
    __shared__ int carry;
    int t = threadIdx.x;
    if (t == 0) carry = 0;
    __syncthreads();
    for (int base = 0; base < m; base += 256) {
        int i = base + t;
        int v = (i < m) ? part[i] : 0;
        sh[t] = v;
        __syncthreads();
        for (int off = 1; off < 256; off <<= 1) {
            int u = (t >= off) ? sh[t - off] : 0;
            __syncthreads();
            sh[t] += u;
            __syncthreads();
        }
        if (i < m) part[i] = sh[t] - v + carry;
        __syncthreads();
        if (t == 255) carry += sh[255];
        __syncthreads();
    }
}

__global__ void scan3_kernel(int* __restrict__ rp, const int* __restrict__ part, int n) {
    int i = blockIdx.x * blockDim.x + threadIdx.x;
    if (i < n) rp[i] += part[i >> 10];
}

// ---- bf16 helpers ------------------------------------------------------

__device__ inline unsigned bf16rne(float f) {
    unsigned u = __float_as_uint(f);
    return (u + 0x7fffu + ((u >> 16) & 1u)) >> 16;
}
__device__ inline float bfl(unsigned u) { return __uint_as_float(u << 16); }
__device__ inline float bfh(unsigned u) { return __uint_as_float(u & 0xffff0000u); }

// ---- fused pull + pack-emission (4-way unrolled gathers) ---------------

struct EmitArg {
    const float* nrm;
    unsigned*    hsb;
    const float* W;
    int relu;
    int on;
};

__global__ void pull_emit_kernel(const int* __restrict__ rp, const int* __restrict__ col,
                                 const unsigned* __restrict__ hsb_in, const float* __restrict__ nrm,
                                 const float* __restrict__ b, float* __restrict__ out,
                                 const float* __restrict__ stat_p, int row_lo, int write_h,
                                 EmitArg em0, EmitArg em1) {
    __shared__ float W0[1280];
    __shared__ float W1[1280];
    __shared__ float rowbuf[32][41];
    int t = threadIdx.x;
    if (em0.on) for (int i = t; i < 1280; i += 256) W0[i] = em0.W[i];
    if (em1.on) for (int i = t; i < 1280; i += 256) W1[i] = em1.W[i];
    int tid = blockIdx.x * 256 + t;
    int rr = tid >> 3;
    int r = row_lo + rr;
    int j = tid & 7;
    int hw = j * 2;
    int ea = rp[r], eb = rp[r + 1];
    uint2 sv = *(const uint2*)(hsb_in + (size_t)r * 16 + hw);
    float a0 = bfl(sv.x), a1 = bfh(sv.x), a2 = bfl(sv.y), a3 = bfh(sv.y);
    int e = ea;
    for (; e + 4 <= eb; e += 4) {                   // 4-way unroll: 4 gathers in flight
        int s0 = col[e];
        int s1 = col[e + 1];
        int s2 = col[e + 2];
        int s3 = col[e + 3];
        uint2 v0 = *(const uint2*)(hsb_in + (size_t)s0 * 16 + hw);
        uint2 v1 = *(const uint2*)(hsb_in + (size_t)s1 * 16 + hw);
        uint2 v2 = *(const uint2*)(hsb_in + (size_t)s2 * 16 + hw);
        uint2 v3 = *(const uint2*)(hsb_in + (size_t)s3 * 16 + hw);
        a0 += bfl(v0.x) + bfl(v1.x) + bfl(v2.x) + bfl(v3.x);
        a1 += bfh(v0.x) + bfh(v1.x) + bfh(v2.x) + bfh(v3.x);
        a2 += bfl(v0.y) + bfl(v1.y) + bfl(v2.y) + bfl(v3.y);
        a3 += bfh(v0.y) + bfh(v1.y) + bfh(v2.y) + bfh(v3.y);
    }
    for (; e < eb; e++) {
        int s = col[e];
        uint2 v = *(const uint2*)(hsb_in + (size_t)s * 16 + hw);
        a0 += bfl(v.x); a1 += bfh(v.x); a2 += bfl(v.y); a3 += bfh(v.y);
    }
    float nm = nrm[r];
    int q = j * 4;
    float4 bv = *(const float4*)(b + q);
    float o0 = fmaf(a0, nm, bv.x), o1 = fmaf(a1, nm, bv.y);
    float o2 = fmaf(a2, nm, bv.z), o3 = fmaf(a3, nm, bv.w);
    if (write_h)
        *(float4*)(out + (size_t)r * DYNF + q) = make_float4(o0, o1, o2, o3);
    if (!em0.on && !em1.on) return;
    int lrow = t >> 3;
    rowbuf[lrow][q] = o0; rowbuf[lrow][q + 1] = o1;
    rowbuf[lrow][q + 2] = o2; rowbuf[lrow][q + 3] = o3;
    rowbuf[lrow][32 + j] = stat_p[(size_t)rr * 8 + j];
    __syncthreads();
    if (em0.on) {
        float nmc = em0.nrm[rr];
        float r0 = 0, r1 = 0, r2 = 0, r3 = 0;
#pragma unroll
        for (int k = 0; k < 40; k++) {
            float v = rowbuf[lrow][k];
            if (k < 32 && em0.relu) v = fmaxf(v, 0.f);
            const float* Wp = &W0[k * 32 + q];
            r0 = fmaf(v, Wp[0], r0); r1 = fmaf(v, Wp[1], r1);
            r2 = fmaf(v, Wp[2], r2); r3 = fmaf(v, Wp[3], r3);
        }
        unsigned u0 = bf16rne(r0 * nmc) | (bf16rne(r1 * nmc) << 16);
        unsigned u1 = bf16rne(r2 * nmc) | (bf16rne(r3 * nmc) << 16);
        *(uint2*)(em0.hsb + (size_t)rr * 16 + hw) = make_uint2(u0, u1);
    }
    if (em1.on) {
        float nmc = em1.nrm[rr];
        float r0 = 0, r1 = 0, r2 = 0, r3 = 0;
#pragma unroll
        for (int k = 0; k < 40; k++) {
            float v = rowbuf[lrow][k];
            if (k < 32 && em1.relu) v = fmaxf(v, 0.f);
            const float* Wp = &W1[k * 32 + q];
            r0 = fmaf(v, Wp[0], r0); r1 = fmaf(v, Wp[1], r1);
            r2 = fmaf(v, Wp[2], r2); r3 = fmaf(v, Wp[3], r3);
        }
        unsigned u0 = bf16rne(r0 * nmc) | (bf16rne(r1 * nmc) << 16);
        unsigned u1 = bf16rne(r2 * nmc) | (bf16rne(r3 * nmc) << 16);
        *(uint2*)(em1.hsb + (size_t)rr * 16 + hw) = make_uint2(u0, u1);
    }
}

// ---- up conv: bf16 xs, 8 thr/row edge-parallel pull + emission ---------

__global__ void xsb_kernel(const float* __restrict__ x, const float* __restrict__ nrm,
                           uint2* __restrict__ xsb, int n) {
    int r = blockIdx.x * blockDim.x + threadIdx.x;
    if (r >= n) return;
    float nm = nrm[r];
    float4 v = *(const float4*)(x + (size_t)r * 4);
    xsb[r] = make_uint2(bf16rne(v.x * nm) | (bf16rne(v.y * nm) << 16),
                        bf16rne(v.z * nm) | (bf16rne(v.w * nm) << 16));
}

__global__ void init_out_kernel(float* out, const float* __restrict__ lin_b) {
    int i = threadIdx.x;
    if (i < GG) out[i] = lin_b[0];
}

struct UpEmit {
    const float* n0; const float* n1; const float* n2; const float* n3;
    unsigned* h0; unsigned* h1; unsigned* h2; unsigned* h3;
};

__global__ void pull4mm_emit_kernel(const int* __restrict__ rp0, const int* __restrict__ col,
                                    const uint2* __restrict__ xsb, const float* __restrict__ Wup,
                                    const float* __restrict__ nrm, const float* __restrict__ bup,
                                    const float* __restrict__ Win, const float* __restrict__ Wf,
                                    const float* __restrict__ stat, UpEmit ue) {
    __shared__ float Ws[128];
    __shared__ float bs[32];
    __shared__ float Wa[1280];
    __shared__ float Wb[1280];
    __shared__ float rowbuf[32][41];
    int t = threadIdx.x;
    for (int i = t; i < 128; i += 256) Ws[i] = Wup[i];
    if (t < 32) bs[t] = bup[t];
    for (int i = t; i < 1280; i += 256) { Wa[i] = Win[i]; Wb[i] = Wf[i]; }
    __syncthreads();
    int tid = blockIdx.x * 256 + t;
    int g = tid >> 3;
    int j = t & 7;
    int ea = rp0[g], eb = rp0[g + 1];
    float a0 = 0.f, a1 = 0.f, a2 = 0.f, a3 = 0.f;
    int e = ea + j;
    for (; e + 8 < eb; e += 16) {
        uint2 v0 = xsb[col[e]];
        uint2 v1 = xsb[col[e + 8]];
        a0 += bfl(v0.x) + bfl(v1.x); a1 += bfh(v0.x) + bfh(v1.x);
        a2 += bfl(v0.y) + bfl(v1.y); a3 += bfh(v0.y) + bfh(v1.y);
    }
    if (e < eb) {
        uint2 v = xsb[col[e]];
        a0 += bfl(v.x); a1 += bfh(v.x); a2 += bfl(v.y); a3 += bfh(v.y);
    }
#pragma unroll
    for (int m = 1; m < 8; m <<= 1) {
        a0 += __shfl_xor(a0, m);
        a1 += __shfl_xor(a1, m);
        a2 += __shfl_xor(a2, m);
        a3 += __shfl_xor(a3, m);
    }
    uint2 sv = xsb[g];
    a0 += bfl(sv.x); a1 += bfh(sv.x); a2 += bfl(sv.y); a3 += bfh(sv.y);
    float nm = nrm[g];
    int q = j * 4;
    int lrow = t >> 3;
#pragma unroll
    for (int d = 0; d < 4; d++) {
        float s = a0 * Ws[q + d] + a1 * Ws[32 + q + d] + a2 * Ws[64 + q + d] + a3 * Ws[96 + q + d];
        rowbuf[lrow][q + d] = fmaf(s, nm, bs[q + d]);
    }
    rowbuf[lrow][32 + j] = stat[(size_t)g * 8 + j];
    __syncthreads();
    int l = g >> 16;
    const float* W = (l == 0) ? Wa : Wb;
    const float* nc = (l == 0) ? ue.n0 : (l == 1) ? ue.n1 : (l == 2) ? ue.n2 : ue.n3;
    unsigned* hb = (l == 0) ? ue.h0 : (l == 1) ? ue.h1 : (l == 2) ? ue.h2 : ue.h3;
    float nmc = nc[g];
    float r0 = 0, r1 = 0, r2 = 0, r3 = 0;
#pragma unroll
    for (int k = 0; k < 40; k++) {
        float v = rowbuf[lrow][k];
        const float* Wp = &W[k * 32 + q];
        r0 = fmaf(v, Wp[0], r0); r1 = fmaf(v, Wp[1], r1);
        r2 = fmaf(v, Wp[2], r2); r3 = fmaf(v, Wp[3], r3);
    }
    unsigned u0 = bf16rne(r0 * nmc) | (bf16rne(r1 * nmc) << 16);
    unsigned u1 = bf16rne(r2 * nmc) | (bf16rne(r3 * nmc) << 16);
    *(uint2*)(hb + (size_t)g * 16 + j * 2) = make_uint2(u0, u1);
}

// ---- epilogue ----------------------------------------------------------

__global__ void pool_kernel(const float* __restrict__ h, const int* __restrict__ gids,
                            const float* __restrict__ linW, float* out) {
    __shared__ float part[GG];
    int t = threadIdx.x;
    if (t < GG) part[t] = 0.f;
    __syncthreads();
    int r = blockIdx.x * blockDim.x + t;
    float dotv = 0.f;
    const float4* hp = (const float4*)(h + (size_t)r * DYNF);
#pragma unroll
    for (int q = 0; q < 8; q++) {
        float4 v = hp[q];
        dotv += fmaxf(v.x, 0.f) * linW[q * 4 + 0] + fmaxf(v.y, 0.f) * linW[q * 4 + 1] +
                fmaxf(v.z, 0.f) * linW[q * 4 + 2] + fmaxf(v.w, 0.f) * linW[q * 4 + 3];
    }
    atomicAdd(&part[gids[r]], dotv);
    __syncthreads();
    if (t < GG) unsafeAtomicAdd(&out[t], part[t]);
}

// ------------------------------------------------------------------------

extern "C" void kernel_launch(void* const* d_in, const int* in_sizes, int n_in,
                              void* d_out, int out_size, void* d_ws, size_t ws_size,
                              hipStream_t stream) {
    const float* x     = (const float*)d_in[0];
    const float* stat  = (const float*)d_in[1];
    const int*   e_up  = (const int*)d_in[2];
    const int*   e_in  = (const int*)d_in[3];
    const int*   e_f   = (const int*)d_in[4];
    const int*   e_b   = (const int*)d_in[5];
    const int*   gids  = (const int*)d_in[6];
    const float* W_up  = (const float*)d_in[7];
    const float* b_up  = (const float*)d_in[8];
    const float* W_in  = (const float*)d_in[9];
    const float* b_in  = (const float*)d_in[10];
    const float* W_f   = (const float*)d_in[11];
    const float* b_f   = (const float*)d_in[12];
    const float* W_b   = (const float*)d_in[13];
    const float* b_b   = (const float*)d_in[14];
    const float* lin_W = (const float*)d_in[15];
    const float* lin_b = (const float*)d_in[16];
    float* out = (float*)d_out;

    // ---- workspace carve (~172 MB peak) ----
    float*    norms = (float*)d_ws;                              // NS_TOT
    int*      rp    = (int*)(norms + NS_TOT);                    // NS_TOT+1
    int*      col   = rp + NS_TOT + 1;                           // CO_TOT
    unsigned* H0    = (unsigned*)(col + CO_TOT);                 // conv region base
    float*    h     = (float*)H0;                                // NN*32 f32
    unsigned* hsbp  = H0 + (size_t)NN * DYNF;                    // pack pool: 16*NLK rows *16 u32
    uint2*    xsb   = (uint2*)(hsbp + (size_t)16 * NLK * 16);    // NN uint2 (dedicated)
    unsigned* pairs = H0;                                        // build alias (CO_TOT u32)
    int*      hmat  = (int*)(H0 + CO_TOT);                       // HM
    int*      smat  = hmat + HM;                                 // HM
    int*      part  = smat + HM;                                 // >= 560

    unsigned* SA  = hsbp + (size_t)0  * SLOT_U;
    unsigned* SB  = hsbp + (size_t)1  * SLOT_U;
    unsigned* SC  = hsbp + (size_t)2  * SLOT_U;
    unsigned* SD  = hsbp + (size_t)3  * SLOT_U;
    unsigned* F0b = hsbp + (size_t)4  * SLOT_U;
    unsigned* F1b = hsbp + (size_t)6  * SLOT_U;
    unsigned* F2b = hsbp + (size_t)8  * SLOT_U;
    unsigned* B0b = hsbp + (size_t)10 * SLOT_U;
    unsigned* B1b = hsbp + (size_t)12 * SLOT_U;
    unsigned* B2b = hsbp + (size_t)14 * SLOT_U;

    // ---- build: zero-global-atomic radix partition + LDS-staged passes ----
    hist_part_kernel<<<NB, 1024, 0, stream>>>(e_up, e_in, e_f, e_b, hmat);
    scan1_kernel<<<HM / 1024, 1024, 0, stream>>>(hmat, smat, part, HM);
    scan2_kernel<<<1, 256, 0, stream>>>(part, HM / 1024);
    scan3_kernel<<<cdiv(HM, 256), 256, 0, stream>>>(smat, part, HM);
    scatter_part_kernel<<<NB, 1024, 0, stream>>>(e_up, e_in, e_f, e_b, hmat, smat, pairs);
    group_kernel<<<NBUCK, 1024, 0, stream>>>(pairs, smat, col, rp, norms);

    // ---- up conv: bf16 xs; fused pull4 + matmul + per-layer pack ----
    xsb_kernel<<<cdiv(NN, 256), 256, 0, stream>>>(x, norms + NS_UP, xsb, NN);
    init_out_kernel<<<1, 64, 0, stream>>>(out, lin_b);
    UpEmit ue;
    ue.n0 = norms + NS_IN(0);
    ue.n1 = norms + NS_F(0);
    ue.n2 = norms + NS_F(1) - NLK;
    ue.n3 = norms + NS_F(2) - 2 * NLK;
    ue.h0 = SA;
    ue.h1 = F0b;
    ue.h2 = F1b - (size_t)SLOT_U;
    ue.h3 = F2b - (size_t)2 * SLOT_U;
    pull4mm_emit_kernel<<<(NN * 8) / 256, 256, 0, stream>>>(rp + NS_UP, col, xsb, W_up,
                                                            norms + NS_UP, b_up, W_in, W_f, stat, ue);

    // ---- fused conv chain: 13 pulls per pass, each emits its consumers' packs ----
    auto EM = [&](const float* n, unsigned* hb, const float* W, int rl) {
        EmitArg e; e.nrm = n; e.hsb = hb; e.W = W; e.relu = rl; e.on = 1; return e;
    };
    EmitArg OFF; OFF.nrm = nullptr; OFF.hsb = nullptr; OFF.W = nullptr; OFF.relu = 0; OFF.on = 0;

    auto P = [&](unsigned* buf, int ns, const float* bias, int gbase, int row_lo,
                 int wh, EmitArg a, EmitArg c) {
        pull_emit_kernel<<<(NLK * 8) / 256, 256, 0, stream>>>(
            rp + ns, col, buf, norms + ns, bias, h + (size_t)gbase * DYNF,
            stat + (size_t)(gbase + row_lo) * STATF, row_lo, wh, a, c);
    };

    for (int p = 0; p < 2; p++) {
        // A-loop
        P(SA, NS_IN(0), b_in, 0, 0, 0,
          EM(norms + NS_F(0), F0b, W_f, 0), EM(norms + NS_B(0), B0b, W_b, 1));        // I0
        P(F0b, NS_F(0), b_f, 0, NLK, 0,
          EM(norms + NS_IN(1), SB, W_in, 0), OFF);                                    // F0
        P(SB, NS_IN(1), b_in, NLK, 0, 0,
          EM(norms + NS_F(1), F1b, W_f, 0), EM(norms + NS_B(1), B1b, W_b, 1));        // I1
        P(F1b, NS_F(1), b_f, NLK, NLK, 0,
          EM(norms + NS_IN(2), SC, W_in, 0), OFF);                                    // F1
        P(SC, NS_IN(2), b_in, 2 * NLK, 0, 0,
          EM(norms + NS_F(2), F2b, W_f, 0), EM(norms + NS_B(2), B2b, W_b, 1));        // I2
        P(F2b, NS_F(2), b_f, 2 * NLK, NLK, 0,
          EM(norms + NS_IN(3), SA, W_in, 0), OFF);                                    // F2
        P(SA, NS_IN(3), b_in, 3 * NLK, 0, (p == 1),
          EM(norms + NS_B(2) + NLK, B2b + (size_t)SLOT_U, W_b, 1),
          p == 0 ? EM(norms + NS_F(2) + NLK, F2b + (size_t)SLOT_U, W_f, 1) : OFF);    // I3
        // B-loop
        P(B2b, NS_B(2), b_b, 2 * NLK, 0, 0,
          EM(norms + NS_IN(2), SC, W_in, 0), OFF);                                    // B2
        P(SC, NS_IN(2), b_in, 2 * NLK, 0, (p == 1),
          EM(norms + NS_B(1) + NLK, B1b + (size_t)SLOT_U, W_b, 0),
          p == 0 ? EM(norms + NS_F(1) + NLK, F1b + (size_t)SLOT_U, W_f, 1) : OFF);    // i2
        P(B1b, NS_B(1), b_b, NLK, 0, 0,
          EM(norms + NS_IN(1), SB, W_in, 0), OFF);                                    // B1
        P(SB, NS_IN(1), b_in, NLK, 0, (p == 1),
          EM(norms + NS_B(0) + NLK, B0b + (size_t)SLOT_U, W_b, 0),
          p == 0 ? EM(norms + NS_F(0) + NLK, F0b + (size_t)SLOT_U, W_f, 1) : OFF);    // i1
        P(B0b, NS_B(0), b_b, 0, 0, 0,
          EM(norms + NS_IN(0), SD, W_in, 0), OFF);                                    // B0
        P(SD, NS_IN(0), b_in, 0, 0, (p == 1),
          p == 0 ? EM(norms + NS_IN(0), SA, W_in, 1) : OFF, OFF);                     // i0
    }

    pool_kernel<<<NN / 256, 256, 0, stream>>>(h, gids, lin_W, out);
}

// Round 22
// 743.362 us; speedup vs baseline: 1.0893x; 1.0186x over previous
//
#include <hip/hip_runtime.h>

#define NLK 65536
#define NN (NLK * 4)        // 262144 nodes
#define DYNF 32
#define STATF 8
#define GG 64
#define EUP 4194304
#define EIN 1048576
#define EFB 1048576

// unified row space: [up: NN][inner: 4*NLK][fwd: 3*2NLK][bwd: 3*2NLK]
#define NS_UP    0
#define NS_IN(l) (NN + (l) * NLK)
#define NS_F(l)  (NN + 4 * NLK + (l) * 2 * NLK)
#define NS_B(l)  (NN + 10 * NLK + (l) * 2 * NLK)
#define NS_TOT   (NN + 16 * NLK)                    // 1,310,720
#define CO_TOT   (EUP + 4 * EIN + 6 * EFB)          // 14,680,064

#define CHUNK 32768                                 // edges per partition block
#define NB    (CO_TOT / CHUNK)                      // 448 partition blocks
#define BROWS 1024                                  // rows per bucket
#define NBUCK (NS_TOT / BROWS)                      // 1280 buckets
#define HM    (NBUCK * NB)                          // 573,440
#define SCAP  20480                                 // group LDS sort capacity

#define SLOT_U (NLK * 16)

static inline int cdiv(long a, int b) { return (int)((a + b - 1) / b); }

// ---- which list does partition block b cover? --------------------------
__device__ inline void cdecode(int b, const int* e_up, const int* e_in,
                               const int* e_f, const int* e_b,
                               const int*& srcp, const int*& dstp, int& ns, int& e0) {
    if (b < EUP / CHUNK) { srcp = e_up; dstp = e_up + EUP; ns = NS_UP; e0 = b * CHUNK; return; }
    int t = b - EUP / CHUNK;
    int list = t >> 5;                               // 32 blocks per small list
    e0 = (t & 31) * CHUNK;
    if (list < 4) {
        srcp = e_in + (size_t)(2 * list) * EIN; dstp = srcp + EIN; ns = NS_IN(list);
    } else if (list < 7) {
        int l = list - 4;
        srcp = e_f + (size_t)(2 * l) * EFB; dstp = srcp + EFB; ns = NS_F(l);
    } else {
        int l = list - 7;
        srcp = e_b + (size_t)(2 * l) * EFB; dstp = srcp + EFB; ns = NS_B(l);
    }
}

// ---- pass 1: per-block LDS bucket histogram (1024 thr, int4 loads) -----
__global__ void hist_part_kernel(const int* __restrict__ e_up, const int* __restrict__ e_in,
                                 const int* __restrict__ e_f, const int* __restrict__ e_b,
                                 int* __restrict__ hmat) {
    __shared__ int lh[NBUCK];
    for (int k = threadIdx.x; k < NBUCK; k += 1024) lh[k] = 0;
    __syncthreads();
    const int *srcp, *dstp; int ns, e0;
    cdecode(blockIdx.x, e_up, e_in, e_f, e_b, srcp, dstp, ns, e0);
    for (int j = 0; j < CHUNK / 4096; j++) {        // 8 iters, 4 edges/thread/iter
        int4 d4 = *(const int4*)(dstp + e0 + (j * 1024 + threadIdx.x) * 4);
        atomicAdd(&lh[(ns + d4.x) >> 10], 1);
        atomicAdd(&lh[(ns + d4.y) >> 10], 1);
        atomicAdd(&lh[(ns + d4.z) >> 10], 1);
        atomicAdd(&lh[(ns + d4.w) >> 10], 1);
    }
    __syncthreads();
    for (int k = threadIdx.x; k < NBUCK; k += 1024)
        hmat[(size_t)k * NB + blockIdx.x] = lh[k];
}

// ---- pass 2: LDS-staged bucket sort -> coalesced slice flush (int4) ----
__global__ void scatter_part_kernel(const int* __restrict__ e_up, const int* __restrict__ e_in,
                                    const int* __restrict__ e_f, const int* __restrict__ e_b,
                                    const int* __restrict__ hmat, const int* __restrict__ smat,
                                    unsigned* __restrict__ pairs) {
    __shared__ unsigned srt[CHUNK];                 // 128 KB
    __shared__ int ls[NBUCK + 1];
    __shared__ int gbase[NBUCK];
    __shared__ int lcur[NBUCK];
    __shared__ int ssum[1024];
    int t = threadIdx.x;
    int b = blockIdx.x;
    const int *srcp, *dstp; int ns, e0;
    cdecode(b, e_up, e_in, e_f, e_b, srcp, dstp, ns, e0);
    int a0 = (2 * t < NBUCK) ? hmat[(size_t)(2 * t) * NB + b] : 0;
    int a1 = (2 * t + 1 < NBUCK) ? hmat[(size_t)(2 * t + 1) * NB + b] : 0;
    if (2 * t < NBUCK) gbase[2 * t] = smat[(size_t)(2 * t) * NB + b];
    if (2 * t + 1 < NBUCK) gbase[2 * t + 1] = smat[(size_t)(2 * t + 1) * NB + b];
    if (2 * t < NBUCK) lcur[2 * t] = 0;
    if (2 * t + 1 < NBUCK) lcur[2 * t + 1] = 0;
    int gsum = a0 + a1;
    ssum[t] = gsum;
    __syncthreads();
    for (int off = 1; off < 1024; off <<= 1) {
        int u = (t >= off) ? ssum[t - off] : 0;
        __syncthreads();
        ssum[t] += u;
        __syncthreads();
    }
    int run = ssum[t] - gsum;
    if (2 * t < NBUCK) ls[2 * t] = run;
    if (2 * t + 1 < NBUCK) ls[2 * t + 1] = run + a0;
    if (t == 0) ls[NBUCK] = CHUNK;                  // sentinel
    __syncthreads();
    for (int j = 0; j < CHUNK / 4096; j++) {        // int4: 4 edges/thread/iter
        int idx = e0 + (j * 1024 + t) * 4;
        int4 d4 = *(const int4*)(dstp + idx);
        int4 s4 = *(const int4*)(srcp + idx);
        int g, k, pos;
        g = ns + d4.x; k = g >> 10; pos = ls[k] + atomicAdd(&lcur[k], 1);
        srt[pos] = ((unsigned)s4.x << 10) | (unsigned)(g & (BROWS - 1));
        g = ns + d4.y; k = g >> 10; pos = ls[k] + atomicAdd(&lcur[k], 1);
        srt[pos] = ((unsigned)s4.y << 10) | (unsigned)(g & (BROWS - 1));
        g = ns + d4.z; k = g >> 10; pos = ls[k] + atomicAdd(&lcur[k], 1);
        srt[pos] = ((unsigned)s4.z << 10) | (unsigned)(g & (BROWS - 1));
        g = ns + d4.w; k = g >> 10; pos = ls[k] + atomicAdd(&lcur[k], 1);
        srt[pos] = ((unsigned)s4.w << 10) | (unsigned)(g & (BROWS - 1));
    }
    __syncthreads();
    int wave = t >> 6;
    int lane = t & 63;
    for (int k = wave; k < NBUCK; k += 16) {
        int lo = ls[k];
        int n = ls[k + 1] - lo;
        int dst = gbase[k];
        for (int i = lane; i < n; i += 64)
            pairs[dst + i] = srt[lo + i];
    }
}

// ---- pass 3: per-bucket group; LDS-staged sort -> sequential col (1024 thr)
__global__ void group_kernel(const unsigned* __restrict__ pairs, const int* __restrict__ smat,
                             int* __restrict__ col, int* __restrict__ rp,
                             float* __restrict__ norms) {
    __shared__ int srt[SCAP];
    __shared__ int lcnt[BROWS];
    __shared__ int roff[BROWS];
    __shared__ int lcur[BROWS];
    __shared__ int ssum[1024];
    int k = blockIdx.x;
    int t = threadIdx.x;
    int base = smat[(size_t)k * NB];
    int end  = (k + 1 < NBUCK) ? smat[(size_t)(k + 1) * NB] : CO_TOT;
    int nb = end - base;
    lcnt[t] = 0;
    lcur[t] = 0;
    __syncthreads();
    for (int i = base + t; i < end; i += 1024)
        atomicAdd(&lcnt[pairs[i] & (BROWS - 1)], 1);
    __syncthreads();
    int a0 = lcnt[t];
    ssum[t] = a0;
    __syncthreads();
    for (int off = 1; off < 1024; off <<= 1) {
        int u = (t >= off) ? ssum[t - off] : 0;
        __syncthreads();
        ssum[t] += u;
        __syncthreads();
    }
    int gex = ssum[t] - a0;
    roff[t] = gex;
    int row = k * BROWS + t;
    rp[row] = base + gex;
    norms[row] = rsqrtf((float)(a0 + 1));           // +1 self-loop
    if (k == 0 && t == 0) rp[NS_TOT] = CO_TOT;
    __syncthreads();
    if (nb <= SCAP) {
        for (int i = base + t; i < end; i += 1024) {
            unsigned p = pairs[i];
            int rl = p & (BROWS - 1);
            int pos = roff[rl] + atomicAdd(&lcur[rl], 1);
            srt[pos] = (int)(p >> 10);
        }
        __syncthreads();
        for (int j = t; j < nb; j += 1024)
            col[base + j] = srt[j];
    } else {
        for (int i = base + t; i < end; i += 1024) {
            unsigned p = pairs[i];
            int rl = p & (BROWS - 1);
            int pos = base + roff[rl] + atomicAdd(&lcur[rl], 1);
            col[pos] = (int)(p >> 10);
        }
    }
}

// ---- global scan ------------------------------------------------------

__global__ void scan1_kernel(const int* __restrict__ cnt, int* __restrict__ rp,
                             int* __restrict__ part, int n) {
    __shared__ int sh[1024];
    int t = threadIdx.x;
    int i = blockIdx.x * 1024 + t;
    int v = (i < n) ? cnt[i] : 0;
    sh[t] = v;
    __syncthreads();
    for (int off = 1; off < 1024; off <<= 1) {
        int u = (t >= off) ? sh[t - off] : 0;
        __syncthreads();
        sh[t] += u;
        __syncthreads();
    }
    if (i < n) rp[i] = sh[t] - v;
    if (t == 1023) part[blockIdx.x] = sh[1023];
}

__global__ void scan2_kernel(int* part, int m) {
    __shared__ int sh[256];
    __shared__ int carry;
    int t = threadIdx.x;
    if (t == 0) carry = 0;
    __syncthreads();
    for (int base = 0; base < m; base += 256) {
        int i = base + t;
        int v = (i < m) ? part[i] : 0;
        sh[t] = v;
        __syncthreads();
        for (int off = 1; off < 256; off <<= 1) {
            int u = (t >= off) ? sh[t - off] : 0;
            __syncthreads();
            sh[t] += u;
            __syncthreads();
        }
        if (i < m) part[i] = sh[t] - v + carry;
        __syncthreads();
        if (t == 255) carry += sh[255];
        __syncthreads();
    }
}

__global__ void scan3_kernel(int* __restrict__ rp, const int* __restrict__ part, int n) {
    int i = blockIdx.x * blockDim.x + threadIdx.x;
    if (i < n) rp[i] += part[i >> 10];
}

// ---- bf16 helpers ------------------------------------------------------

__device__ inline unsigned bf16rne(float f) {
    unsigned u = __float_as_uint(f);
    return (u + 0x7fffu + ((u >> 16) & 1u)) >> 16;
}
__device__ inline float bfl(unsigned u) { return __uint_as_float(u << 16); }
__device__ inline float bfh(unsigned u) { return __uint_as_float(u & 0xffff0000u); }

// ---- fused pull + pack-emission (8-way unrolled gathers) ---------------

struct EmitArg {
    const float* nrm;
    unsigned*    hsb;
    const float* W;
    int relu;
    int on;
};

__global__ void pull_emit_kernel(const int* __restrict__ rp, const int* __restrict__ col,
                                 const unsigned* __restrict__ hsb_in, const float* __restrict__ nrm,
                                 const float* __restrict__ b, float* __restrict__ out,
                                 const float* __restrict__ stat_p, int row_lo, int write_h,
                                 EmitArg em0, EmitArg em1) {
    __shared__ float W0[1280];
    __shared__ float W1[1280];
    __shared__ float rowbuf[32][41];
    int t = threadIdx.x;
    if (em0.on) for (int i = t; i < 1280; i += 256) W0[i] = em0.W[i];
    if (em1.on) for (int i = t; i < 1280; i += 256) W1[i] = em1.W[i];
    int tid = blockIdx.x * 256 + t;
    int rr = tid >> 3;
    int r = row_lo + rr;
    int j = tid & 7;
    int hw = j * 2;
    int ea = rp[r], eb = rp[r + 1];
    uint2 sv = *(const uint2*)(hsb_in + (size_t)r * 16 + hw);
    float a0 = bfl(sv.x), a1 = bfh(sv.x), a2 = bfl(sv.y), a3 = bfh(sv.y);
    int e = ea;
    for (; e + 8 <= eb; e += 8) {                   // 8-way unroll: 8 gathers in flight
        int s0 = col[e];
        int s1 = col[e + 1];
        int s2 = col[e + 2];
        int s3 = col[e + 3];
        int s4 = col[e + 4];
        int s5 = col[e + 5];
        int s6 = col[e + 6];
        int s7 = col[e + 7];
        uint2 v0 = *(const uint2*)(hsb_in + (size_t)s0 * 16 + hw);
        uint2 v1 = *(const uint2*)(hsb_in + (size_t)s1 * 16 + hw);
        uint2 v2 = *(const uint2*)(hsb_in + (size_t)s2 * 16 + hw);
        uint2 v3 = *(const uint2*)(hsb_in + (size_t)s3 * 16 + hw);
        uint2 v4 = *(const uint2*)(hsb_in + (size_t)s4 * 16 + hw);
        uint2 v5 = *(const uint2*)(hsb_in + (size_t)s5 * 16 + hw);
        uint2 v6 = *(const uint2*)(hsb_in + (size_t)s6 * 16 + hw);
        uint2 v7 = *(const uint2*)(hsb_in + (size_t)s7 * 16 + hw);
        a0 += bfl(v0.x) + bfl(v1.x) + bfl(v2.x) + bfl(v3.x)
            + bfl(v4.x) + bfl(v5.x) + bfl(v6.x) + bfl(v7.x);
        a1 += bfh(v0.x) + bfh(v1.x) + bfh(v2.x) + bfh(v3.x)
            + bfh(v4.x) + bfh(v5.x) + bfh(v6.x) + bfh(v7.x);
        a2 += bfl(v0.y) + bfl(v1.y) + bfl(v2.y) + bfl(v3.y)
            + bfl(v4.y) + bfl(v5.y) + bfl(v6.y) + bfl(v7.y);
        a3 += bfh(v0.y) + bfh(v1.y) + bfh(v2.y) + bfh(v3.y)
            + bfh(v4.y) + bfh(v5.y) + bfh(v6.y) + bfh(v7.y);
    }
    for (; e + 4 <= eb; e += 4) {
        int s0 = col[e];
        int s1 = col[e + 1];
        int s2 = col[e + 2];
        int s3 = col[e + 3];
        uint2 v0 = *(const uint2*)(hsb_in + (size_t)s0 * 16 + hw);
        uint2 v1 = *(const uint2*)(hsb_in + (size_t)s1 * 16 + hw);
        uint2 v2 = *(const uint2*)(hsb_in + (size_t)s2 * 16 + hw);
        uint2 v3 = *(const uint2*)(hsb_in + (size_t)s3 * 16 + hw);
        a0 += bfl(v0.x) + bfl(v1.x) + bfl(v2.x) + bfl(v3.x);
        a1 += bfh(v0.x) + bfh(v1.x) + bfh(v2.x) + bfh(v3.x);
        a2 += bfl(v0.y) + bfl(v1.y) + bfl(v2.y) + bfl(v3.y);
        a3 += bfh(v0.y) + bfh(v1.y) + bfh(v2.y) + bfh(v3.y);
    }
    for (; e < eb; e++) {
        int s = col[e];
        uint2 v = *(const uint2*)(hsb_in + (size_t)s * 16 + hw);
        a0 += bfl(v.x); a1 += bfh(v.x); a2 += bfl(v.y); a3 += bfh(v.y);
    }
    float nm = nrm[r];
    int q = j * 4;
    float4 bv = *(const float4*)(b + q);
    float o0 = fmaf(a0, nm, bv.x), o1 = fmaf(a1, nm, bv.y);
    float o2 = fmaf(a2, nm, bv.z), o3 = fmaf(a3, nm, bv.w);
    if (write_h)
        *(float4*)(out + (size_t)r * DYNF + q) = make_float4(o0, o1, o2, o3);
    if (!em0.on && !em1.on) return;
    int lrow = t >> 3;
    rowbuf[lrow][q] = o0; rowbuf[lrow][q + 1] = o1;
    rowbuf[lrow][q + 2] = o2; rowbuf[lrow][q + 3] = o3;
    rowbuf[lrow][32 + j] = stat_p[(size_t)rr * 8 + j];
    __syncthreads();
    if (em0.on) {
        float nmc = em0.nrm[rr];
        float r0 = 0, r1 = 0, r2 = 0, r3 = 0;
#pragma unroll
        for (int k = 0; k < 40; k++) {
            float v = rowbuf[lrow][k];
            if (k < 32 && em0.relu) v = fmaxf(v, 0.f);
            const float* Wp = &W0[k * 32 + q];
            r0 = fmaf(v, Wp[0], r0); r1 = fmaf(v, Wp[1], r1);
            r2 = fmaf(v, Wp[2], r2); r3 = fmaf(v, Wp[3], r3);
        }
        unsigned u0 = bf16rne(r0 * nmc) | (bf16rne(r1 * nmc) << 16);
        unsigned u1 = bf16rne(r2 * nmc) | (bf16rne(r3 * nmc) << 16);
        *(uint2*)(em0.hsb + (size_t)rr * 16 + hw) = make_uint2(u0, u1);
    }
    if (em1.on) {
        float nmc = em1.nrm[rr];
        float r0 = 0, r1 = 0, r2 = 0, r3 = 0;
#pragma unroll
        for (int k = 0; k < 40; k++) {
            float v = rowbuf[lrow][k];
            if (k < 32 && em1.relu) v = fmaxf(v, 0.f);
            const float* Wp = &W1[k * 32 + q];
            r0 = fmaf(v, Wp[0], r0); r1 = fmaf(v, Wp[1], r1);
            r2 = fmaf(v, Wp[2], r2); r3 = fmaf(v, Wp[3], r3);
        }
        unsigned u0 = bf16rne(r0 * nmc) | (bf16rne(r1 * nmc) << 16);
        unsigned u1 = bf16rne(r2 * nmc) | (bf16rne(r3 * nmc) << 16);
        *(uint2*)(em1.hsb + (size_t)rr * 16 + hw) = make_uint2(u0, u1);
    }
}

// ---- up conv: bf16 xs, 8 thr/row edge-parallel pull + emission ---------

__global__ void xsb_kernel(const float* __restrict__ x, const float* __restrict__ nrm,
                           uint2* __restrict__ xsb, int n) {
    int r = blockIdx.x * blockDim.x + threadIdx.x;
    if (r >= n) return;
    float nm = nrm[r];
    float4 v = *(const float4*)(x + (size_t)r * 4);
    xsb[r] = make_uint2(bf16rne(v.x * nm) | (bf16rne(v.y * nm) << 16),
                        bf16rne(v.z * nm) | (bf16rne(v.w * nm) << 16));
}

__global__ void init_out_kernel(float* out, const float* __restrict__ lin_b) {
    int i = threadIdx.x;
    if (i < GG) out[i] = lin_b[0];
}

struct UpEmit {
    const float* n0; const float* n1; const float* n2; const float* n3;
    unsigned* h0; unsigned* h1; unsigned* h2; unsigned* h3;
};

__global__ void pull4mm_emit_kernel(const int* __restrict__ rp0, const int* __restrict__ col,
                                    const uint2* __restrict__ xsb, const float* __restrict__ Wup,
                                    const float* __restrict__ nrm, const float* __restrict__ bup,
                                    const float* __restrict__ Win, const float* __restrict__ Wf,
                                    const float* __restrict__ stat, UpEmit ue) {
    __shared__ float Ws[128];
    __shared__ float bs[32];
    __shared__ float Wa[1280];
    __shared__ float Wb[1280];
    __shared__ float rowbuf[32][41];
    int t = threadIdx.x;
    for (int i = t; i < 128; i += 256) Ws[i] = Wup[i];
    if (t < 32) bs[t] = bup[t];
    for (int i = t; i < 1280; i += 256) { Wa[i] = Win[i]; Wb[i] = Wf[i]; }
    __syncthreads();
    int tid = blockIdx.x * 256 + t;
    int g = tid >> 3;
    int j = t & 7;
    int ea = rp0[g], eb = rp0[g + 1];
    float a0 = 0.f, a1 = 0.f, a2 = 0.f, a3 = 0.f;
    int e = ea + j;
    for (; e + 8 < eb; e += 16) {
        uint2 v0 = xsb[col[e]];
        uint2 v1 = xsb[col[e + 8]];
        a0 += bfl(v0.x) + bfl(v1.x); a1 += bfh(v0.x) + bfh(v1.x);
        a2 += bfl(v0.y) + bfl(v1.y); a3 += bfh(v0.y) + bfh(v1.y);
    }
    if (e < eb) {
        uint2 v = xsb[col[e]];
        a0 += bfl(v.x); a1 += bfh(v.x); a2 += bfl(v.y); a3 += bfh(v.y);
    }
#pragma unroll
    for (int m = 1; m < 8; m <<= 1) {
        a0 += __shfl_xor(a0, m);
        a1 += __shfl_xor(a1, m);
        a2 += __shfl_xor(a2, m);
        a3 += __shfl_xor(a3, m);
    }
    uint2 sv = xsb[g];
    a0 += bfl(sv.x); a1 += bfh(sv.x); a2 += bfl(sv.y); a3 += bfh(sv.y);
    float nm = nrm[g];
    int q = j * 4;
    int lrow = t >> 3;
#pragma unroll
    for (int d = 0; d < 4; d++) {
        float s = a0 * Ws[q + d] + a1 * Ws[32 + q + d] + a2 * Ws[64 + q + d] + a3 * Ws[96 + q + d];
        rowbuf[lrow][q + d] = fmaf(s, nm, bs[q + d]);
    }
    rowbuf[lrow][32 + j] = stat[(size_t)g * 8 + j];
    __syncthreads();
    int l = g >> 16;
    const float* W = (l == 0) ? Wa : Wb;
    const float* nc = (l == 0) ? ue.n0 : (l == 1) ? ue.n1 : (l == 2) ? ue.n2 : ue.n3;
    unsigned* hb = (l == 0) ? ue.h0 : (l == 1) ? ue.h1 : (l == 2) ? ue.h2 : ue.h3;
    float nmc = nc[g];
    float r0 = 0, r1 = 0, r2 = 0, r3 = 0;
#pragma unroll
    for (int k = 0; k < 40; k++) {
        float v = rowbuf[lrow][k];
        const float* Wp = &W[k * 32 + q];
        r0 = fmaf(v, Wp[0], r0); r1 = fmaf(v, Wp[1], r1);
        r2 = fmaf(v, Wp[2], r2); r3 = fmaf(v, Wp[3], r3);
    }
    unsigned u0 = bf16rne(r0 * nmc) | (bf16rne(r1 * nmc) << 16);
    unsigned u1 = bf16rne(r2 * nmc) | (bf16rne(r3 * nmc) << 16);
    *(uint2*)(hb + (size_t)g * 16 + j * 2) = make_uint2(u0, u1);
}

// ---- epilogue ----------------------------------------------------------

__global__ void pool_kernel(const float* __restrict__ h, const int* __restrict__ gids,
                            const float* __restrict__ linW, float* out) {
    __shared__ float part[GG];
    int t = threadIdx.x;
    if (t < GG) part[t] = 0.f;
    __syncthreads();
    int r = blockIdx.x * blockDim.x + t;
    float dotv = 0.f;
    const float4* hp = (const float4*)(h + (size_t)r * DYNF);
#pragma unroll
    for (int q = 0; q < 8; q++) {
        float4 v = hp[q];
        dotv += fmaxf(v.x, 0.f) * linW[q * 4 + 0] + fmaxf(v.y, 0.f) * linW[q * 4 + 1] +
                fmaxf(v.z, 0.f) * linW[q * 4 + 2] + fmaxf(v.w, 0.f) * linW[q * 4 + 3];
    }
    atomicAdd(&part[gids[r]], dotv);
    __syncthreads();
    if (t < GG) unsafeAtomicAdd(&out[t], part[t]);
}

// ------------------------------------------------------------------------

extern "C" void kernel_launch(void* const* d_in, const int* in_sizes, int n_in,
                              void* d_out, int out_size, void* d_ws, size_t ws_size,
                              hipStream_t stream) {
    const float* x     = (const float*)d_in[0];
    const float* stat  = (const float*)d_in[1];
    const int*   e_up  = (const int*)d_in[2];
    const int*   e_in  = (const int*)d_in[3];
    const int*   e_f   = (const int*)d_in[4];
    const int*   e_b   = (const int*)d_in[5];
    const int*   gids  = (const int*)d_in[6];
    const float* W_up  = (const float*)d_in[7];
    const float* b_up  = (const float*)d_in[8];
    const float* W_in  = (const float*)d_in[9];
    const float* b_in  = (const float*)d_in[10];
    const float* W_f   = (const float*)d_in[11];
    const float* b_f   = (const float*)d_in[12];
    const float* W_b   = (const float*)d_in[13];
    const float* b_b   = (const float*)d_in[14];
    const float* lin_W = (const float*)d_in[15];
    const float* lin_b = (const float*)d_in[16];
    float* out = (float*)d_out;

    // ---- workspace carve (~172 MB peak) ----
    float*    norms = (float*)d_ws;                              // NS_TOT
    int*      rp    = (int*)(norms + NS_TOT);                    // NS_TOT+1
    int*      col   = rp + NS_TOT + 1;                           // CO_TOT
    unsigned* H0    = (unsigned*)(col + CO_TOT);                 // conv region base
    float*    h     = (float*)H0;                                // NN*32 f32
    unsigned* hsbp  = H0 + (size_t)NN * DYNF;                    // pack pool: 16*NLK rows *16 u32
    uint2*    xsb   = (uint2*)(hsbp + (size_t)16 * NLK * 16);    // NN uint2 (dedicated)
    unsigned* pairs = H0;                                        // build alias (CO_TOT u32)
    int*      hmat  = (int*)(H0 + CO_TOT);                       // HM
    int*      smat  = hmat + HM;                                 // HM
    int*      part  = smat + HM;                                 // >= 560

    unsigned* SA  = hsbp + (size_t)0  * SLOT_U;
    unsigned* SB  = hsbp + (size_t)1  * SLOT_U;
    unsigned* SC  = hsbp + (size_t)2  * SLOT_U;
    unsigned* SD  = hsbp + (size_t)3  * SLOT_U;
    unsigned* F0b = hsbp + (size_t)4  * SLOT_U;
    unsigned* F1b = hsbp + (size_t)6  * SLOT_U;
    unsigned* F2b = hsbp + (size_t)8  * SLOT_U;
    unsigned* B0b = hsbp + (size_t)10 * SLOT_U;
    unsigned* B1b = hsbp + (size_t)12 * SLOT_U;
    unsigned* B2b = hsbp + (size_t)14 * SLOT_U;

    // ---- build: zero-global-atomic radix partition + LDS-staged passes ----
    hist_part_kernel<<<NB, 1024, 0, stream>>>(e_up, e_in, e_f, e_b, hmat);
    scan1_kernel<<<HM / 1024, 1024, 0, stream>>>(hmat, smat, part, HM);
    scan2_kernel<<<1, 256, 0, stream>>>(part, HM / 1024);
    scan3_kernel<<<cdiv(HM, 256), 256, 0, stream>>>(smat, part, HM);
    scatter_part_kernel<<<NB, 1024, 0, stream>>>(e_up, e_in, e_f, e_b, hmat, smat, pairs);
    group_kernel<<<NBUCK, 1024, 0, stream>>>(pairs, smat, col, rp, norms);

    // ---- up conv: bf16 xs; fused pull4 + matmul + per-layer pack ----
    xsb_kernel<<<cdiv(NN, 256), 256, 0, stream>>>(x, norms + NS_UP, xsb, NN);
    init_out_kernel<<<1, 64, 0, stream>>>(out, lin_b);
    UpEmit ue;
    ue.n0 = norms + NS_IN(0);
    ue.n1 = norms + NS_F(0);
    ue.n2 = norms + NS_F(1) - NLK;
    ue.n3 = norms + NS_F(2) - 2 * NLK;
    ue.h0 = SA;
    ue.h1 = F0b;
    ue.h2 = F1b - (size_t)SLOT_U;
    ue.h3 = F2b - (size_t)2 * SLOT_U;
    pull4mm_emit_kernel<<<(NN * 8) / 256, 256, 0, stream>>>(rp + NS_UP, col, xsb, W_up,
                                                            norms + NS_UP, b_up, W_in, W_f, stat, ue);

    // ---- fused conv chain: 13 pulls per pass, each emits its consumers' packs ----
    auto EM = [&](const float* n, unsigned* hb, const float* W, int rl) {
        EmitArg e; e.nrm = n; e.hsb = hb; e.W = W; e.relu = rl; e.on = 1; return e;
    };
    EmitArg OFF; OFF.nrm = nullptr; OFF.hsb = nullptr; OFF.W = nullptr; OFF.relu = 0; OFF.on = 0;

    auto P = [&](unsigned* buf, int ns, const float* bias, int gbase, int row_lo,
                 int wh, EmitArg a, EmitArg c) {
        pull_emit_kernel<<<(NLK * 8) / 256, 256, 0, stream>>>(
            rp + ns, col, buf, norms + ns, bias, h + (size_t)gbase * DYNF,
            stat + (size_t)(gbase + row_lo) * STATF, row_lo, wh, a, c);
    };

    for (int p = 0; p < 2; p++) {
        // A-loop
        P(SA, NS_IN(0), b_in, 0, 0, 0,
          EM(norms + NS_F(0), F0b, W_f, 0), EM(norms + NS_B(0), B0b, W_b, 1));        // I0
        P(F0b, NS_F(0), b_f, 0, NLK, 0,
          EM(norms + NS_IN(1), SB, W_in, 0), OFF);                                    // F0
        P(SB, NS_IN(1), b_in, NLK, 0, 0,
          EM(norms + NS_F(1), F1b, W_f, 0), EM(norms + NS_B(1), B1b, W_b, 1));        // I1
        P(F1b, NS_F(1), b_f, NLK, NLK, 0,
          EM(norms + NS_IN(2), SC, W_in, 0), OFF);                                    // F1
        P(SC, NS_IN(2), b_in, 2 * NLK, 0, 0,
          EM(norms + NS_F(2), F2b, W_f, 0), EM(norms + NS_B(2), B2b, W_b, 1));        // I2
        P(F2b, NS_F(2), b_f, 2 * NLK, NLK, 0,
          EM(norms + NS_IN(3), SA, W_in, 0), OFF);                                    // F2
        P(SA, NS_IN(3), b_in, 3 * NLK, 0, (p == 1),
          EM(norms + NS_B(2) + NLK, B2b + (size_t)SLOT_U, W_b, 1),
          p == 0 ? EM(norms + NS_F(2) + NLK, F2b + (size_t)SLOT_U, W_f, 1) : OFF);    // I3
        // B-loop
        P(B2b, NS_B(2), b_b, 2 * NLK, 0, 0,
          EM(norms + NS_IN(2), SC, W_in, 0), OFF);                                    // B2
        P(SC, NS_IN(2), b_in, 2 * NLK, 0, (p == 1),
          EM(norms + NS_B(1) + NLK, B1b + (size_t)SLOT_U, W_b, 0),
          p == 0 ? EM(norms + NS_F(1) + NLK, F1b + (size_t)SLOT_U, W_f, 1) : OFF);    // i2
        P(B1b, NS_B(1), b_b, NLK, 0, 0,
          EM(norms + NS_IN(1), SB, W_in, 0), OFF);                                    // B1
        P(SB, NS_IN(1), b_in, NLK, 0, (p == 1),
          EM(norms + NS_B(0) + NLK, B0b + (size_t)SLOT_U, W_b, 0),
          p == 0 ? EM(norms + NS_F(0) + NLK, F0b + (size_t)SLOT_U, W_f, 1) : OFF);    // i1
        P(B0b, NS_B(0), b_b, 0, 0, 0,
          EM(norms + NS_IN(0), SD, W_in, 0), OFF);                                    // B0
        P(SD, NS_IN(0), b_in, 0, 0, (p == 1),
          p == 0 ? EM(norms + NS_IN(0), SA, W_in, 1) : OFF, OFF);                     // i0
    }

    pool_kernel<<<NN / 256, 256, 0, stream>>>(h, gids, lin_W, out);
}